// Round 1
// baseline (12418.782 us; speedup 1.0000x reference)
//
#include <hip/hip_runtime.h>

#define NEG_SLOPE 0.2f
// enc(-inf): bits(-inf)=0xFF800000 -> ~ = 0x007FFFFF (order-preserving unsigned encoding)
#define ENC_NEG_INF 0x007FFFFFu

__device__ __forceinline__ unsigned enc_f(float f) {
    unsigned u = __float_as_uint(f);
    return (u & 0x80000000u) ? ~u : (u | 0x80000000u);
}
__device__ __forceinline__ float dec_f(unsigned v) {
    unsigned u = (v & 0x80000000u) ? (v & 0x7FFFFFFFu) : ~v;
    return __uint_as_float(u);
}

// out[n,c] = sum_k x[n,k] * W[k,c]   (x: [N,K], W: [K,C])
template <int K>
__global__ __launch_bounds__(256) void gemm_kernel(
    const float* __restrict__ x, const float* __restrict__ W,
    float* __restrict__ out, int N, int C) {
    int idx = blockIdx.x * blockDim.x + threadIdx.x;
    if (idx >= N * C) return;
    int n = idx / C, c = idx % C;
    const float* xr = x + (size_t)n * K;
    float acc = 0.f;
#pragma unroll
    for (int k = 0; k < K; ++k) acc += xr[k] * W[k * C + c];
    out[idx] = acc;
}

// el[n,h] = sum_d feat[n,h,d]*al[h,d]; er likewise
__global__ __launch_bounds__(256) void attn_proj_kernel(
    const float* __restrict__ feat, const float* __restrict__ al,
    const float* __restrict__ ar, float* __restrict__ el, float* __restrict__ er,
    int N, int H, int D) {
    int idx = blockIdx.x * blockDim.x + threadIdx.x;
    if (idx >= N * H) return;
    int n = idx / H, h = idx % H;
    const float* f = feat + (size_t)n * H * D + h * D;
    float sl = 0.f, sr = 0.f;
    for (int d = 0; d < D; ++d) {
        sl += f[d] * al[h * D + d];
        sr += f[d] * ar[h * D + d];
    }
    el[idx] = sl;
    er[idx] = sr;
}

__global__ __launch_bounds__(256) void init_emax_kernel(unsigned* __restrict__ emax, int n) {
    int idx = blockIdx.x * blockDim.x + threadIdx.x;
    if (idx < n) emax[idx] = ENC_NEG_INF;
}

__global__ __launch_bounds__(256) void edge_max_kernel(
    const int* __restrict__ src, const int* __restrict__ dst,
    const float* __restrict__ el, const float* __restrict__ er,
    unsigned* __restrict__ emax, int E, int H) {
    int idx = blockIdx.x * blockDim.x + threadIdx.x;
    if (idx >= E * H) return;
    int e = idx / H, h = idx % H;
    int s = src[e], d = dst[e];
    float v = el[s * H + h] + er[d * H + h];
    v = v > 0.f ? v : NEG_SLOPE * v;
    atomicMax(&emax[d * H + h], enc_f(v));
}

// accumulate unnormalized: acc[dst,h,:] += ex*feat[src,h,:], denom[dst,h] += ex
__global__ __launch_bounds__(256) void edge_acc_kernel(
    const int* __restrict__ src, const int* __restrict__ dst,
    const float* __restrict__ el, const float* __restrict__ er,
    const unsigned* __restrict__ emax, const float* __restrict__ feat,
    float* __restrict__ acc, float* __restrict__ denom, int E, int H, int D) {
    int idx = blockIdx.x * blockDim.x + threadIdx.x;
    if (idx >= E * H) return;
    int e = idx / H, h = idx % H;
    int s = src[e], d = dst[e];
    float v = el[s * H + h] + er[d * H + h];
    v = v > 0.f ? v : NEG_SLOPE * v;
    float ex = expf(v - dec_f(emax[d * H + h]));
    atomicAdd(&denom[d * H + h], ex);
    const float* f = feat + ((size_t)s * H + h) * D;
    float* a = acc + ((size_t)d * H + h) * D;
    for (int dd = 0; dd < D; ++dd) atomicAdd(&a[dd], ex * f[dd]);
}

// layer1 finalize: out[n,h,d] = acc/denomguard + b, then h_out[n,d]=relu(mean_h(out))
__global__ __launch_bounds__(256) void finalize1_kernel(
    const float* __restrict__ acc, const float* __restrict__ denom,
    const float* __restrict__ b, float* __restrict__ hout, int N, int H, int D) {
    int idx = blockIdx.x * blockDim.x + threadIdx.x;
    if (idx >= N * D) return;
    int n = idx / D, dd = idx % D;
    float s = 0.f;
    for (int h = 0; h < H; ++h) {
        float dn = denom[n * H + h];
        dn = (dn == 0.f) ? 1.f : dn;
        s += acc[((size_t)n * H + h) * D + dd] / dn + b[h * D + dd];
    }
    s /= (float)H;
    hout[idx] = s > 0.f ? s : 0.f;
}

// layer2 finalize in place on d_out: out = out/denomguard + b  (H=1)
__global__ __launch_bounds__(256) void finalize2_kernel(
    float* __restrict__ out, const float* __restrict__ denom,
    const float* __restrict__ b, int N, int D) {
    int idx = blockIdx.x * blockDim.x + threadIdx.x;
    if (idx >= N * D) return;
    int n = idx / D, dd = idx % D;
    float dn = denom[n];
    dn = (dn == 0.f) ? 1.f : dn;
    out[idx] = out[idx] / dn + b[dd];
}

extern "C" void kernel_launch(void* const* d_in, const int* in_sizes, int n_in,
                              void* d_out, int out_size, void* d_ws, size_t ws_size,
                              hipStream_t stream) {
    const float* x   = (const float*)d_in[0];
    const int*   src = (const int*)d_in[1];
    const int*   dst = (const int*)d_in[2];
    const float* W1  = (const float*)d_in[3];
    const float* al1 = (const float*)d_in[4];
    const float* ar1 = (const float*)d_in[5];
    const float* b1  = (const float*)d_in[6];
    const float* W2  = (const float*)d_in[7];
    const float* al2 = (const float*)d_in[8];
    const float* ar2 = (const float*)d_in[9];
    const float* b2  = (const float*)d_in[10];

    const int E = in_sizes[1];
    const int N = in_sizes[0] / 128;
    const int H1 = 4, D1 = 32, C1 = 128;  // layer 1
    const int D2 = 16;                    // layer 2 (H=1)

    // workspace layout (floats)
    float* p = (float*)d_ws;
    float* feat1 = p;            p += (size_t)N * C1;
    float* acc1  = p;            p += (size_t)N * C1;
    float* el1   = p;            p += (size_t)N * H1;
    float* er1   = p;            p += (size_t)N * H1;
    unsigned* emax1 = (unsigned*)p; p += (size_t)N * H1;
    float* denom1 = p;           p += (size_t)N * H1;
    float* hbuf  = p;            p += (size_t)N * D1;
    // layer-2 buffers overlay feat1 (dead after layer-1 edge accumulate)
    float* feat2 = feat1;
    float* el2   = feat1 + (size_t)N * D2;
    float* er2   = el2 + N;
    unsigned* emax2 = (unsigned*)(er2 + N);
    float* denom2 = (float*)(emax2 + N);

    const int TB = 256;
    auto blocks = [&](long long n) { return (int)((n + TB - 1) / TB); };

    // ---- layer 1 ----
    hipMemsetAsync(acc1, 0, (size_t)N * C1 * sizeof(float), stream);
    hipMemsetAsync(denom1, 0, (size_t)N * H1 * sizeof(float), stream);
    init_emax_kernel<<<blocks(N * H1), TB, 0, stream>>>(emax1, N * H1);

    gemm_kernel<128><<<blocks((long long)N * C1), TB, 0, stream>>>(x, W1, feat1, N, C1);
    attn_proj_kernel<<<blocks(N * H1), TB, 0, stream>>>(feat1, al1, ar1, el1, er1, N, H1, D1);
    edge_max_kernel<<<blocks((long long)E * H1), TB, 0, stream>>>(src, dst, el1, er1, emax1, E, H1);
    edge_acc_kernel<<<blocks((long long)E * H1), TB, 0, stream>>>(src, dst, el1, er1, emax1,
                                                                  feat1, acc1, denom1, E, H1, D1);
    finalize1_kernel<<<blocks(N * D1), TB, 0, stream>>>(acc1, denom1, b1, hbuf, N, H1, D1);

    // ---- layer 2 ----
    gemm_kernel<32><<<blocks((long long)N * D2), TB, 0, stream>>>(hbuf, W2, feat2, N, D2);
    attn_proj_kernel<<<blocks(N), TB, 0, stream>>>(feat2, al2, ar2, el2, er2, N, 1, D2);
    hipMemsetAsync(d_out, 0, (size_t)N * D2 * sizeof(float), stream);
    hipMemsetAsync(denom2, 0, (size_t)N * sizeof(float), stream);
    init_emax_kernel<<<blocks(N), TB, 0, stream>>>(emax2, N);
    edge_max_kernel<<<blocks(E), TB, 0, stream>>>(src, dst, el2, er2, emax2, E, 1);
    edge_acc_kernel<<<blocks(E), TB, 0, stream>>>(src, dst, el2, er2, emax2,
                                                  feat2, (float*)d_out, denom2, E, 1, D2);
    finalize2_kernel<<<blocks(N * D2), TB, 0, stream>>>((float*)d_out, denom2, b2, N, D2);
}

// Round 2
// 1114.640 us; speedup vs baseline: 11.1415x; 11.1415x over previous
//
#include <hip/hip_runtime.h>

#define NEG_SLOPE 0.2f

// ---------- dense: out[n,c] = sum_k x[n,k] * W[k,c] ----------
template <int K>
__global__ __launch_bounds__(256) void gemm_kernel(
    const float* __restrict__ x, const float* __restrict__ W,
    float* __restrict__ out, int N, int C) {
    int idx = blockIdx.x * blockDim.x + threadIdx.x;
    if (idx >= N * C) return;
    int n = idx / C, c = idx % C;
    const float* xr = x + (size_t)n * K;
    float acc = 0.f;
#pragma unroll
    for (int k = 0; k < K; ++k) acc += xr[k] * W[k * C + c];
    out[idx] = acc;
}

// ---------- el[n,h] = <feat[n,h,:], al[h,:]>; er likewise ----------
__global__ __launch_bounds__(256) void attn_proj_kernel(
    const float* __restrict__ feat, const float* __restrict__ al,
    const float* __restrict__ ar, float* __restrict__ el, float* __restrict__ er,
    int N, int H, int D) {
    int idx = blockIdx.x * blockDim.x + threadIdx.x;
    if (idx >= N * H) return;
    int n = idx / H, h = idx % H;
    const float* f = feat + (size_t)n * H * D + h * D;
    float sl = 0.f, sr = 0.f;
    for (int d = 0; d < D; ++d) {
        sl += f[d] * al[h * D + d];
        sr += f[d] * ar[h * D + d];
    }
    el[idx] = sl;
    er[idx] = sr;
}

// ---------- CSR build ----------
__global__ __launch_bounds__(256) void hist_kernel(
    const int* __restrict__ dst, int* __restrict__ deg, int E) {
    int e = blockIdx.x * blockDim.x + threadIdx.x;
    if (e < E) atomicAdd(&deg[dst[e]], 1);
}

// per-block exclusive scan of deg -> rowptr(partial); block totals -> blocksum
__global__ __launch_bounds__(256) void scan_block_kernel(
    const int* __restrict__ deg, int* __restrict__ rowptr,
    int* __restrict__ blocksum, int n) {
    __shared__ int tmp[256];
    int tid = threadIdx.x;
    int i = blockIdx.x * 256 + tid;
    int v = (i < n) ? deg[i] : 0;
    tmp[tid] = v;
    __syncthreads();
    for (int off = 1; off < 256; off <<= 1) {
        int t = (tid >= off) ? tmp[tid - off] : 0;
        __syncthreads();
        tmp[tid] += t;
        __syncthreads();
    }
    if (i < n) rowptr[i] = tmp[tid] - v;  // exclusive
    if (tid == 255) blocksum[blockIdx.x] = tmp[255];
}

// single-block exclusive scan of blocksum[0..nb) -> blockoff
__global__ __launch_bounds__(512) void scan_top_kernel(
    const int* __restrict__ blocksum, int* __restrict__ blockoff, int nb) {
    __shared__ int tmp[512];
    int tid = threadIdx.x;
    int v = (tid < nb) ? blocksum[tid] : 0;
    tmp[tid] = v;
    __syncthreads();
    for (int off = 1; off < 512; off <<= 1) {
        int t = (tid >= off) ? tmp[tid - off] : 0;
        __syncthreads();
        tmp[tid] += t;
        __syncthreads();
    }
    if (tid < nb) blockoff[tid] = tmp[tid] - v;
}

__global__ __launch_bounds__(256) void scan_add_kernel(
    int* __restrict__ rowptr, int* __restrict__ cursor,
    const int* __restrict__ blockoff, int n) {
    int i = blockIdx.x * 256 + threadIdx.x;
    if (i < n) {
        int r = rowptr[i] + blockoff[blockIdx.x];
        rowptr[i] = r;
        cursor[i] = r;
    }
}

// esrc[pos] = src[e], grouped by dst
__global__ __launch_bounds__(256) void scatter_kernel(
    const int* __restrict__ src, const int* __restrict__ dst,
    int* __restrict__ cursor, int* __restrict__ esrc, int E) {
    int e = blockIdx.x * blockDim.x + threadIdx.x;
    if (e >= E) return;
    int d = dst[e];
    int pos = atomicAdd(&cursor[d], 1);
    esrc[pos] = src[e];
}

// ---------- pull aggregation: group of D lanes per (node, head) ----------
// out[n,h,dd] = (sum_i exp(lrelu(el[s_i,h]+er[n,h])) * feat[s_i,h,dd]) / sumex + b[h,dd]
template <int H, int D>
__global__ __launch_bounds__(256) void pull_kernel(
    const int* __restrict__ rowptr, const int* __restrict__ deg,
    const int* __restrict__ esrc, const float* __restrict__ el,
    const float* __restrict__ er, const float* __restrict__ feat,
    const float* __restrict__ b, float* __restrict__ outp, int N) {
    int idx = blockIdx.x * blockDim.x + threadIdx.x;
    int dd = idx % D;
    int group = idx / D;
    int n = group / H, h = group % H;
    if (n >= N) return;
    int start = rowptr[n];
    int cnt = deg[n];
    float er_nh = er[n * H + h];
    float acc = 0.f, sumex = 0.f;
    for (int i = 0; i < cnt; ++i) {
        int s = esrc[start + i];
        float v = el[s * H + h] + er_nh;
        v = v > 0.f ? v : NEG_SLOPE * v;
        float ex = expf(v);
        acc += ex * feat[((size_t)s * H + h) * D + dd];
        sumex += ex;
    }
    float dn = (sumex == 0.f) ? 1.f : sumex;
    outp[((size_t)n * H + h) * D + dd] = acc / dn + b[h * D + dd];
}

// ---------- layer1 epilogue: hbuf[n,dd] = relu(mean_h out1[n,h,dd]) ----------
__global__ __launch_bounds__(256) void finalize1_kernel(
    const float* __restrict__ out1, float* __restrict__ hout, int N) {
    const int H = 4, D = 32;
    int idx = blockIdx.x * blockDim.x + threadIdx.x;
    if (idx >= N * D) return;
    int n = idx / D, dd = idx % D;
    float s = 0.f;
    for (int h = 0; h < H; ++h) s += out1[((size_t)n * H + h) * D + dd];
    s *= (1.f / (float)H);
    hout[idx] = s > 0.f ? s : 0.f;
}

extern "C" void kernel_launch(void* const* d_in, const int* in_sizes, int n_in,
                              void* d_out, int out_size, void* d_ws, size_t ws_size,
                              hipStream_t stream) {
    const float* x   = (const float*)d_in[0];
    const int*   src = (const int*)d_in[1];
    const int*   dst = (const int*)d_in[2];
    const float* W1  = (const float*)d_in[3];
    const float* al1 = (const float*)d_in[4];
    const float* ar1 = (const float*)d_in[5];
    const float* b1  = (const float*)d_in[6];
    const float* W2  = (const float*)d_in[7];
    const float* al2 = (const float*)d_in[8];
    const float* ar2 = (const float*)d_in[9];
    const float* b2  = (const float*)d_in[10];

    const int E = in_sizes[1];
    const int N = in_sizes[0] / 128;
    const int H1 = 4, D1 = 32, C1 = 128;  // layer 1
    const int D2 = 16;                    // layer 2 (H=1)
    const int NBLK = (N + 255) / 256;     // 391 for N=100000 (<=512 required)

    // ---- workspace layout ----
    char* p = (char*)d_ws;
    auto alloc_f = [&](size_t n) { float* q = (float*)p; p += n * sizeof(float); return q; };
    auto alloc_i = [&](size_t n) { int* q = (int*)p; p += n * sizeof(int); return q; };

    float* feat1 = alloc_f((size_t)N * C1);   // [N,4,32]
    float* out1  = alloc_f((size_t)N * C1);   // layer-1 output [N,4,32]
    float* el1   = alloc_f((size_t)N * H1);
    float* er1   = alloc_f((size_t)N * H1);
    float* hbuf  = alloc_f((size_t)N * D1);   // [N,32]
    float* feat2 = alloc_f((size_t)N * D2);   // [N,16]
    float* el2   = alloc_f(N);
    float* er2   = alloc_f(N);
    int* deg     = alloc_i(N);
    int* rowptr  = alloc_i(N);
    int* cursor  = alloc_i(N);
    int* esrc    = alloc_i(E);
    int* blocksum = alloc_i(NBLK);
    int* blockoff = alloc_i(NBLK);

    const int TB = 256;
    auto blocks = [&](long long n) { return (int)((n + TB - 1) / TB); };

    // ---- CSR build (shared by both layers) ----
    hipMemsetAsync(deg, 0, (size_t)N * sizeof(int), stream);
    hist_kernel<<<blocks(E), TB, 0, stream>>>(dst, deg, E);
    scan_block_kernel<<<NBLK, TB, 0, stream>>>(deg, rowptr, blocksum, N);
    scan_top_kernel<<<1, 512, 0, stream>>>(blocksum, blockoff, NBLK);
    scan_add_kernel<<<NBLK, TB, 0, stream>>>(rowptr, cursor, blockoff, N);
    scatter_kernel<<<blocks(E), TB, 0, stream>>>(src, dst, cursor, esrc, E);

    // ---- layer 1 ----
    gemm_kernel<128><<<blocks((long long)N * C1), TB, 0, stream>>>(x, W1, feat1, N, C1);
    attn_proj_kernel<<<blocks(N * H1), TB, 0, stream>>>(feat1, al1, ar1, el1, er1, N, H1, D1);
    pull_kernel<4, 32><<<blocks((long long)N * H1 * D1), TB, 0, stream>>>(
        rowptr, deg, esrc, el1, er1, feat1, b1, out1, N);
    finalize1_kernel<<<blocks(N * D1), TB, 0, stream>>>(out1, hbuf, N);

    // ---- layer 2 ----
    gemm_kernel<32><<<blocks((long long)N * D2), TB, 0, stream>>>(hbuf, W2, feat2, N, D2);
    attn_proj_kernel<<<blocks(N), TB, 0, stream>>>(feat2, al2, ar2, el2, er2, N, 1, D2);
    pull_kernel<1, 16><<<blocks((long long)N * D2), TB, 0, stream>>>(
        rowptr, deg, esrc, el2, er2, feat2, b2, (float*)d_out, N);
}

// Round 3
// 797.646 us; speedup vs baseline: 15.5693x; 1.3974x over previous
//
#include <hip/hip_runtime.h>

#define NEG_SLOPE 0.2f

// ---------- tiled GEMM for layer 1: K=128, C=128 fixed ----------
// BM=64, BN=128, BK=32; 256 threads; thread tile TM=4 x TN=8.
__global__ __launch_bounds__(256) void gemm1_tiled(
    const float* __restrict__ x, const float* __restrict__ W,
    float* __restrict__ out, int N) {
    const int K = 128, C = 128, BM = 64, BK = 32;
    __shared__ float xs[BK][BM + 4];   // [k][m], pad 4 -> conflict-free b128 reads
    __shared__ float ws[BK][C];        // [k][c]

    const int t = threadIdx.x;
    const int trow = t >> 4;           // 0..15  -> rows trow*4 .. +3
    const int tcol = t & 15;           // 0..15  -> cols tcol*8 .. +7
    const int m0 = blockIdx.x * BM;

    float acc[4][8];
#pragma unroll
    for (int i = 0; i < 4; ++i)
#pragma unroll
        for (int j = 0; j < 8; ++j) acc[i][j] = 0.f;

    for (int k0 = 0; k0 < K; k0 += BK) {
        // load W tile: 32x128 = 1024 float4, 4 per thread; coalesced
        {
            const float4* W4 = (const float4*)(W + k0 * C);
#pragma unroll
            for (int r = 0; r < 4; ++r) {
                int q = t + 256 * r;          // 0..1023
                int k = q >> 5;               // 32 float4 per k-row
                int c4 = q & 31;
                float4 v = W4[k * 32 + c4];
                *((float4*)&ws[k][c4 * 4]) = v;
            }
        }
        // load x tile (transposed): 64 rows x 32 k = 512 float4, 2 per thread
        {
#pragma unroll
            for (int r = 0; r < 2; ++r) {
                int q = t + 256 * r;          // 0..511
                int m = q >> 3;               // 8 float4 per row
                int k4 = q & 7;
                int gm = m0 + m;
                if (gm >= N) gm = N - 1;      // clamp (safe, stores guarded)
                float4 v = *((const float4*)(x + (size_t)gm * K + k0 + k4 * 4));
                xs[k4 * 4 + 0][m] = v.x;
                xs[k4 * 4 + 1][m] = v.y;
                xs[k4 * 4 + 2][m] = v.z;
                xs[k4 * 4 + 3][m] = v.w;
            }
        }
        __syncthreads();

#pragma unroll
        for (int k = 0; k < BK; ++k) {
            float4 a = *((const float4*)&xs[k][trow * 4]);
            float4 b0 = *((const float4*)&ws[k][tcol * 8]);
            float4 b1 = *((const float4*)&ws[k][tcol * 8 + 4]);
            float av[4] = {a.x, a.y, a.z, a.w};
            float bv[8] = {b0.x, b0.y, b0.z, b0.w, b1.x, b1.y, b1.z, b1.w};
#pragma unroll
            for (int i = 0; i < 4; ++i)
#pragma unroll
                for (int j = 0; j < 8; ++j) acc[i][j] += av[i] * bv[j];
        }
        __syncthreads();
    }

    // store
#pragma unroll
    for (int i = 0; i < 4; ++i) {
        int gm = m0 + trow * 4 + i;
        if (gm < N) {
            float* o = out + (size_t)gm * C + tcol * 8;
            *((float4*)o) = make_float4(acc[i][0], acc[i][1], acc[i][2], acc[i][3]);
            *((float4*)(o + 4)) = make_float4(acc[i][4], acc[i][5], acc[i][6], acc[i][7]);
        }
    }
}

// ---------- dense: out[n,c] = sum_k x[n,k] * W[k,c] (layer 2) ----------
template <int K>
__global__ __launch_bounds__(256) void gemm_kernel(
    const float* __restrict__ x, const float* __restrict__ W,
    float* __restrict__ out, int N, int C) {
    int idx = blockIdx.x * blockDim.x + threadIdx.x;
    if (idx >= N * C) return;
    int n = idx / C, c = idx % C;
    const float* xr = x + (size_t)n * K;
    float acc = 0.f;
#pragma unroll
    for (int k = 0; k < K; ++k) acc += xr[k] * W[k * C + c];
    out[idx] = acc;
}

// ---------- el[n,h] = <feat[n,h,:], al[h,:]>; er likewise ----------
__global__ __launch_bounds__(256) void attn_proj_kernel(
    const float* __restrict__ feat, const float* __restrict__ al,
    const float* __restrict__ ar, float* __restrict__ el, float* __restrict__ er,
    int N, int H, int D) {
    int idx = blockIdx.x * blockDim.x + threadIdx.x;
    if (idx >= N * H) return;
    int n = idx / H, h = idx % H;
    const float* f = feat + (size_t)n * H * D + h * D;
    float sl = 0.f, sr = 0.f;
    for (int d = 0; d < D; ++d) {
        sl += f[d] * al[h * D + d];
        sr += f[d] * ar[h * D + d];
    }
    el[idx] = sl;
    er[idx] = sr;
}

// ---------- CSR build ----------
__global__ __launch_bounds__(256) void hist_kernel(
    const int* __restrict__ dst, int* __restrict__ deg, int E) {
    int e = blockIdx.x * blockDim.x + threadIdx.x;
    if (e < E) atomicAdd(&deg[dst[e]], 1);
}

__global__ __launch_bounds__(256) void scan_block_kernel(
    const int* __restrict__ deg, int* __restrict__ rowptr,
    int* __restrict__ blocksum, int n) {
    __shared__ int tmp[256];
    int tid = threadIdx.x;
    int i = blockIdx.x * 256 + tid;
    int v = (i < n) ? deg[i] : 0;
    tmp[tid] = v;
    __syncthreads();
    for (int off = 1; off < 256; off <<= 1) {
        int t = (tid >= off) ? tmp[tid - off] : 0;
        __syncthreads();
        tmp[tid] += t;
        __syncthreads();
    }
    if (i < n) rowptr[i] = tmp[tid] - v;  // exclusive
    if (tid == 255) blocksum[blockIdx.x] = tmp[255];
}

__global__ __launch_bounds__(512) void scan_top_kernel(
    const int* __restrict__ blocksum, int* __restrict__ blockoff, int nb) {
    __shared__ int tmp[512];
    int tid = threadIdx.x;
    int v = (tid < nb) ? blocksum[tid] : 0;
    tmp[tid] = v;
    __syncthreads();
    for (int off = 1; off < 512; off <<= 1) {
        int t = (tid >= off) ? tmp[tid - off] : 0;
        __syncthreads();
        tmp[tid] += t;
        __syncthreads();
    }
    if (tid < nb) blockoff[tid] = tmp[tid] - v;
}

__global__ __launch_bounds__(256) void scan_add_kernel(
    int* __restrict__ rowptr, int* __restrict__ cursor,
    const int* __restrict__ blockoff, int n) {
    int i = blockIdx.x * 256 + threadIdx.x;
    if (i < n) {
        int r = rowptr[i] + blockoff[blockIdx.x];
        rowptr[i] = r;
        cursor[i] = r;
    }
}

__global__ __launch_bounds__(256) void scatter_kernel(
    const int* __restrict__ src, const int* __restrict__ dst,
    int* __restrict__ cursor, int* __restrict__ esrc, int E) {
    int e = blockIdx.x * blockDim.x + threadIdx.x;
    if (e >= E) return;
    int d = dst[e];
    int pos = atomicAdd(&cursor[d], 1);
    esrc[pos] = src[e];
}

// ---------- pull aggregation: group of D lanes per (node, head) ----------
template <int H, int D>
__global__ __launch_bounds__(256) void pull_kernel(
    const int* __restrict__ rowptr, const int* __restrict__ deg,
    const int* __restrict__ esrc, const float* __restrict__ el,
    const float* __restrict__ er, const float* __restrict__ feat,
    const float* __restrict__ b, float* __restrict__ outp, int N) {
    int idx = blockIdx.x * blockDim.x + threadIdx.x;
    int dd = idx % D;
    int group = idx / D;
    int n = group / H, h = group % H;
    if (n >= N) return;
    int start = rowptr[n];
    int cnt = deg[n];
    float er_nh = er[n * H + h];
    float acc = 0.f, sumex = 0.f;
    for (int i = 0; i < cnt; ++i) {
        int s = esrc[start + i];
        float v = el[s * H + h] + er_nh;
        v = v > 0.f ? v : NEG_SLOPE * v;
        float ex = expf(v);
        acc += ex * feat[((size_t)s * H + h) * D + dd];
        sumex += ex;
    }
    float dn = (sumex == 0.f) ? 1.f : sumex;
    outp[((size_t)n * H + h) * D + dd] = acc / dn + b[h * D + dd];
}

// ---------- layer1 epilogue: hbuf[n,dd] = relu(mean_h out1[n,h,dd]) ----------
__global__ __launch_bounds__(256) void finalize1_kernel(
    const float* __restrict__ out1, float* __restrict__ hout, int N) {
    const int H = 4, D = 32;
    int idx = blockIdx.x * blockDim.x + threadIdx.x;
    if (idx >= N * D) return;
    int n = idx / D, dd = idx % D;
    float s = 0.f;
    for (int h = 0; h < H; ++h) s += out1[((size_t)n * H + h) * D + dd];
    s *= (1.f / (float)H);
    hout[idx] = s > 0.f ? s : 0.f;
}

extern "C" void kernel_launch(void* const* d_in, const int* in_sizes, int n_in,
                              void* d_out, int out_size, void* d_ws, size_t ws_size,
                              hipStream_t stream) {
    const float* x   = (const float*)d_in[0];
    const int*   src = (const int*)d_in[1];
    const int*   dst = (const int*)d_in[2];
    const float* W1  = (const float*)d_in[3];
    const float* al1 = (const float*)d_in[4];
    const float* ar1 = (const float*)d_in[5];
    const float* b1  = (const float*)d_in[6];
    const float* W2  = (const float*)d_in[7];
    const float* al2 = (const float*)d_in[8];
    const float* ar2 = (const float*)d_in[9];
    const float* b2  = (const float*)d_in[10];

    const int E = in_sizes[1];
    const int N = in_sizes[0] / 128;
    const int H1 = 4, D1 = 32, C1 = 128;  // layer 1
    const int D2 = 16;                    // layer 2 (H=1)
    const int NBLK = (N + 255) / 256;

    // ---- workspace layout ----
    char* p = (char*)d_ws;
    auto alloc_f = [&](size_t n) { float* q = (float*)p; p += n * sizeof(float); return q; };
    auto alloc_i = [&](size_t n) { int* q = (int*)p; p += n * sizeof(int); return q; };

    float* feat1 = alloc_f((size_t)N * C1);
    float* out1  = alloc_f((size_t)N * C1);
    float* el1   = alloc_f((size_t)N * H1);
    float* er1   = alloc_f((size_t)N * H1);
    float* hbuf  = alloc_f((size_t)N * D1);
    float* feat2 = alloc_f((size_t)N * D2);
    float* el2   = alloc_f(N);
    float* er2   = alloc_f(N);
    int* deg     = alloc_i(N);
    int* rowptr  = alloc_i(N);
    int* cursor  = alloc_i(N);
    int* esrc    = alloc_i(E);
    int* blocksum = alloc_i(NBLK);
    int* blockoff = alloc_i(NBLK);

    const int TB = 256;
    auto blocks = [&](long long n) { return (int)((n + TB - 1) / TB); };

    // ---- CSR build (shared by both layers) ----
    hipMemsetAsync(deg, 0, (size_t)N * sizeof(int), stream);
    hist_kernel<<<blocks(E), TB, 0, stream>>>(dst, deg, E);
    scan_block_kernel<<<NBLK, TB, 0, stream>>>(deg, rowptr, blocksum, N);
    scan_top_kernel<<<1, 512, 0, stream>>>(blocksum, blockoff, NBLK);
    scan_add_kernel<<<NBLK, TB, 0, stream>>>(rowptr, cursor, blockoff, N);
    scatter_kernel<<<blocks(E), TB, 0, stream>>>(src, dst, cursor, esrc, E);

    // ---- layer 1 ----
    gemm1_tiled<<<(N + 63) / 64, TB, 0, stream>>>(x, W1, feat1, N);
    attn_proj_kernel<<<blocks(N * H1), TB, 0, stream>>>(feat1, al1, ar1, el1, er1, N, H1, D1);
    pull_kernel<4, 32><<<blocks((long long)N * H1 * D1), TB, 0, stream>>>(
        rowptr, deg, esrc, el1, er1, feat1, b1, out1, N);
    finalize1_kernel<<<blocks(N * D1), TB, 0, stream>>>(out1, hbuf, N);

    // ---- layer 2 ----
    gemm_kernel<32><<<blocks((long long)N * D2), TB, 0, stream>>>(hbuf, W2, feat2, N, D2);
    attn_proj_kernel<<<blocks(N), TB, 0, stream>>>(feat2, al2, ar2, el2, er2, N, 1, D2);
    pull_kernel<1, 16><<<blocks((long long)N * D2), TB, 0, stream>>>(
        rowptr, deg, esrc, el2, er2, feat2, b2, (float*)d_out, N);
}

// Round 4
// 587.758 us; speedup vs baseline: 21.1291x; 1.3571x over previous
//
#include <hip/hip_runtime.h>

#define NEG_SLOPE 0.2f

// ---------- tiled GEMM for layer 1: K=128, C=128 fixed ----------
// BM=64, BN=128, BK=32; 256 threads; thread tile TM=4 x TN=8.
__global__ __launch_bounds__(256) void gemm1_tiled(
    const float* __restrict__ x, const float* __restrict__ W,
    float* __restrict__ out, int N) {
    const int K = 128, C = 128, BM = 64, BK = 32;
    __shared__ float xs[BK][BM + 4];
    __shared__ float ws[BK][C];

    const int t = threadIdx.x;
    const int trow = t >> 4;
    const int tcol = t & 15;
    const int m0 = blockIdx.x * BM;

    float acc[4][8];
#pragma unroll
    for (int i = 0; i < 4; ++i)
#pragma unroll
        for (int j = 0; j < 8; ++j) acc[i][j] = 0.f;

    for (int k0 = 0; k0 < K; k0 += BK) {
        {
            const float4* W4 = (const float4*)(W + k0 * C);
#pragma unroll
            for (int r = 0; r < 4; ++r) {
                int q = t + 256 * r;
                int k = q >> 5;
                int c4 = q & 31;
                float4 v = W4[k * 32 + c4];
                *((float4*)&ws[k][c4 * 4]) = v;
            }
        }
        {
#pragma unroll
            for (int r = 0; r < 2; ++r) {
                int q = t + 256 * r;
                int m = q >> 3;
                int k4 = q & 7;
                int gm = m0 + m;
                if (gm >= N) gm = N - 1;
                float4 v = *((const float4*)(x + (size_t)gm * K + k0 + k4 * 4));
                xs[k4 * 4 + 0][m] = v.x;
                xs[k4 * 4 + 1][m] = v.y;
                xs[k4 * 4 + 2][m] = v.z;
                xs[k4 * 4 + 3][m] = v.w;
            }
        }
        __syncthreads();

#pragma unroll
        for (int k = 0; k < BK; ++k) {
            float4 a = *((const float4*)&xs[k][trow * 4]);
            float4 b0 = *((const float4*)&ws[k][tcol * 8]);
            float4 b1 = *((const float4*)&ws[k][tcol * 8 + 4]);
            float av[4] = {a.x, a.y, a.z, a.w};
            float bv[8] = {b0.x, b0.y, b0.z, b0.w, b1.x, b1.y, b1.z, b1.w};
#pragma unroll
            for (int i = 0; i < 4; ++i)
#pragma unroll
                for (int j = 0; j < 8; ++j) acc[i][j] += av[i] * bv[j];
        }
        __syncthreads();
    }

#pragma unroll
    for (int i = 0; i < 4; ++i) {
        int gm = m0 + trow * 4 + i;
        if (gm < N) {
            float* o = out + (size_t)gm * C + tcol * 8;
            *((float4*)o) = make_float4(acc[i][0], acc[i][1], acc[i][2], acc[i][3]);
            *((float4*)(o + 4)) = make_float4(acc[i][4], acc[i][5], acc[i][6], acc[i][7]);
        }
    }
}

// ---------- dense: out[n,c] = sum_k x[n,k] * W[k,c] (layer 2) ----------
template <int K>
__global__ __launch_bounds__(256) void gemm_kernel(
    const float* __restrict__ x, const float* __restrict__ W,
    float* __restrict__ out, int N, int C) {
    int idx = blockIdx.x * blockDim.x + threadIdx.x;
    if (idx >= N * C) return;
    int n = idx / C, c = idx % C;
    const float* xr = x + (size_t)n * K;
    float acc = 0.f;
#pragma unroll
    for (int k = 0; k < K; ++k) acc += xr[k] * W[k * C + c];
    out[idx] = acc;
}

// ---------- el[n,h] = <feat[n,h,:], al[h,:]>; er likewise ----------
__global__ __launch_bounds__(256) void attn_proj_kernel(
    const float* __restrict__ feat, const float* __restrict__ al,
    const float* __restrict__ ar, float* __restrict__ el, float* __restrict__ er,
    int N, int H, int D) {
    int idx = blockIdx.x * blockDim.x + threadIdx.x;
    if (idx >= N * H) return;
    int n = idx / H, h = idx % H;
    const float* f = feat + (size_t)n * H * D + h * D;
    float sl = 0.f, sr = 0.f;
    for (int d = 0; d < D; ++d) {
        sl += f[d] * al[h * D + d];
        sr += f[d] * ar[h * D + d];
    }
    el[idx] = sl;
    er[idx] = sr;
}

// ---------- CSR build ----------
__global__ __launch_bounds__(256) void hist_kernel(
    const int* __restrict__ dst, int* __restrict__ deg, int E) {
    int e = blockIdx.x * blockDim.x + threadIdx.x;
    if (e < E) atomicAdd(&deg[dst[e]], 1);
}

__global__ __launch_bounds__(256) void scan_block_kernel(
    const int* __restrict__ deg, int* __restrict__ rowptr,
    int* __restrict__ blocksum, int n) {
    __shared__ int tmp[256];
    int tid = threadIdx.x;
    int i = blockIdx.x * 256 + tid;
    int v = (i < n) ? deg[i] : 0;
    tmp[tid] = v;
    __syncthreads();
    for (int off = 1; off < 256; off <<= 1) {
        int t = (tid >= off) ? tmp[tid - off] : 0;
        __syncthreads();
        tmp[tid] += t;
        __syncthreads();
    }
    if (i < n) rowptr[i] = tmp[tid] - v;  // exclusive
    if (tid == 255) blocksum[blockIdx.x] = tmp[255];
}

__global__ __launch_bounds__(512) void scan_top_kernel(
    const int* __restrict__ blocksum, int* __restrict__ blockoff, int nb) {
    __shared__ int tmp[512];
    int tid = threadIdx.x;
    int v = (tid < nb) ? blocksum[tid] : 0;
    tmp[tid] = v;
    __syncthreads();
    for (int off = 1; off < 512; off <<= 1) {
        int t = (tid >= off) ? tmp[tid - off] : 0;
        __syncthreads();
        tmp[tid] += t;
        __syncthreads();
    }
    if (tid < nb) blockoff[tid] = tmp[tid] - v;
}

__global__ __launch_bounds__(256) void scan_add_kernel(
    int* __restrict__ rowptr, int* __restrict__ cursor,
    const int* __restrict__ blockoff, int n) {
    int i = blockIdx.x * 256 + threadIdx.x;
    if (i < n) {
        int r = rowptr[i] + blockoff[blockIdx.x];
        rowptr[i] = r;
        cursor[i] = r;
    }
}

__global__ __launch_bounds__(256) void scatter_kernel(
    const int* __restrict__ src, const int* __restrict__ dst,
    int* __restrict__ cursor, int* __restrict__ esrc, int E) {
    int e = blockIdx.x * blockDim.x + threadIdx.x;
    if (e >= E) return;
    int d = dst[e];
    int pos = atomicAdd(&cursor[d], 1);
    esrc[pos] = src[e];
}

// ---------- layer-1 pull: 32 lanes per node, all 4 heads at once ----------
// lane -> (h = lane/8, d4 = lane%8); float4 feat loads; fused mean+relu.
__global__ __launch_bounds__(256) void pull1_kernel(
    const int* __restrict__ rowptr, const int* __restrict__ deg,
    const int* __restrict__ esrc, const float* __restrict__ el,
    const float* __restrict__ er, const float* __restrict__ feat,
    const float* __restrict__ b, float* __restrict__ hbuf, int N) {
    int tid = blockIdx.x * 256 + threadIdx.x;
    int node = tid >> 5;
    int lane = threadIdx.x & 31;
    int h = lane >> 3;
    int d4 = lane & 7;
    if (node >= N) return;

    int start = rowptr[node];
    int cnt = deg[node];
    float er_nh = er[node * 4 + h];
    const int* ep = esrc + start;
    const float* fb = feat + h * 32 + d4 * 4;  // + s*128 per edge

    float4 acc = make_float4(0.f, 0.f, 0.f, 0.f);
    float sumex = 0.f;
    for (int i = 0; i < cnt; ++i) {
        int s = ep[i];
        float v = el[s * 4 + h] + er_nh;
        v = v > 0.f ? v : NEG_SLOPE * v;
        float ex = expf(v);
        float4 f = *((const float4*)(fb + (size_t)s * 128));
        acc.x += ex * f.x;
        acc.y += ex * f.y;
        acc.z += ex * f.z;
        acc.w += ex * f.w;
        sumex += ex;
    }
    float inv = 1.f / ((sumex == 0.f) ? 1.f : sumex);
    float4 bb = *((const float4*)(b + h * 32 + d4 * 4));
    float4 o;
    o.x = acc.x * inv + bb.x;
    o.y = acc.y * inv + bb.y;
    o.z = acc.z * inv + bb.z;
    o.w = acc.w * inv + bb.w;
    // mean over heads: reduce across lanes differing in bits 3,4 of lane id
    o.x += __shfl_xor(o.x, 8); o.x += __shfl_xor(o.x, 16);
    o.y += __shfl_xor(o.y, 8); o.y += __shfl_xor(o.y, 16);
    o.z += __shfl_xor(o.z, 8); o.z += __shfl_xor(o.z, 16);
    o.w += __shfl_xor(o.w, 8); o.w += __shfl_xor(o.w, 16);
    if (h == 0) {
        o.x = fmaxf(o.x * 0.25f, 0.f);
        o.y = fmaxf(o.y * 0.25f, 0.f);
        o.z = fmaxf(o.z * 0.25f, 0.f);
        o.w = fmaxf(o.w * 0.25f, 0.f);
        *((float4*)(hbuf + (size_t)node * 32 + d4 * 4)) = o;
    }
}

// ---------- layer-2 pull: 4 lanes per node (H=1, D=16), float4 loads ----------
__global__ __launch_bounds__(256) void pull2_kernel(
    const int* __restrict__ rowptr, const int* __restrict__ deg,
    const int* __restrict__ esrc, const float* __restrict__ el,
    const float* __restrict__ er, const float* __restrict__ feat,
    const float* __restrict__ b, float* __restrict__ outp, int N) {
    int tid = blockIdx.x * 256 + threadIdx.x;
    int node = tid >> 2;
    int d4 = threadIdx.x & 3;
    if (node >= N) return;

    int start = rowptr[node];
    int cnt = deg[node];
    float er_n = er[node];
    const int* ep = esrc + start;
    const float* fb = feat + d4 * 4;  // + s*16 per edge

    float4 acc = make_float4(0.f, 0.f, 0.f, 0.f);
    float sumex = 0.f;
    for (int i = 0; i < cnt; ++i) {
        int s = ep[i];
        float v = el[s] + er_n;
        v = v > 0.f ? v : NEG_SLOPE * v;
        float ex = expf(v);
        float4 f = *((const float4*)(fb + (size_t)s * 16));
        acc.x += ex * f.x;
        acc.y += ex * f.y;
        acc.z += ex * f.z;
        acc.w += ex * f.w;
        sumex += ex;
    }
    float inv = 1.f / ((sumex == 0.f) ? 1.f : sumex);
    float4 bb = *((const float4*)(b + d4 * 4));
    float4 o;
    o.x = acc.x * inv + bb.x;
    o.y = acc.y * inv + bb.y;
    o.z = acc.z * inv + bb.z;
    o.w = acc.w * inv + bb.w;
    *((float4*)(outp + (size_t)node * 16 + d4 * 4)) = o;
}

extern "C" void kernel_launch(void* const* d_in, const int* in_sizes, int n_in,
                              void* d_out, int out_size, void* d_ws, size_t ws_size,
                              hipStream_t stream) {
    const float* x   = (const float*)d_in[0];
    const int*   src = (const int*)d_in[1];
    const int*   dst = (const int*)d_in[2];
    const float* W1  = (const float*)d_in[3];
    const float* al1 = (const float*)d_in[4];
    const float* ar1 = (const float*)d_in[5];
    const float* b1  = (const float*)d_in[6];
    const float* W2  = (const float*)d_in[7];
    const float* al2 = (const float*)d_in[8];
    const float* ar2 = (const float*)d_in[9];
    const float* b2  = (const float*)d_in[10];

    const int E = in_sizes[1];
    const int N = in_sizes[0] / 128;
    const int H1 = 4, D1 = 32, C1 = 128;  // layer 1
    const int D2 = 16;                    // layer 2 (H=1)
    const int NBLK = (N + 255) / 256;

    // ---- workspace layout ----
    char* p = (char*)d_ws;
    auto alloc_f = [&](size_t n) { float* q = (float*)p; p += n * sizeof(float); return q; };
    auto alloc_i = [&](size_t n) { int* q = (int*)p; p += n * sizeof(int); return q; };

    float* feat1 = alloc_f((size_t)N * C1);
    float* el1   = alloc_f((size_t)N * H1);
    float* er1   = alloc_f((size_t)N * H1);
    float* hbuf  = alloc_f((size_t)N * D1);
    float* feat2 = alloc_f((size_t)N * D2);
    float* el2   = alloc_f(N);
    float* er2   = alloc_f(N);
    int* deg     = alloc_i(N);
    int* rowptr  = alloc_i(N);
    int* cursor  = alloc_i(N);
    int* esrc    = alloc_i(E);
    int* blocksum = alloc_i(NBLK);
    int* blockoff = alloc_i(NBLK);

    const int TB = 256;
    auto blocks = [&](long long n) { return (int)((n + TB - 1) / TB); };

    // ---- CSR build (shared by both layers) ----
    hipMemsetAsync(deg, 0, (size_t)N * sizeof(int), stream);
    hist_kernel<<<blocks(E), TB, 0, stream>>>(dst, deg, E);
    scan_block_kernel<<<NBLK, TB, 0, stream>>>(deg, rowptr, blocksum, N);
    scan_top_kernel<<<1, 512, 0, stream>>>(blocksum, blockoff, NBLK);
    scan_add_kernel<<<NBLK, TB, 0, stream>>>(rowptr, cursor, blockoff, N);
    scatter_kernel<<<blocks(E), TB, 0, stream>>>(src, dst, cursor, esrc, E);

    // ---- layer 1 ----
    gemm1_tiled<<<(N + 63) / 64, TB, 0, stream>>>(x, W1, feat1, N);
    attn_proj_kernel<<<blocks(N * H1), TB, 0, stream>>>(feat1, al1, ar1, el1, er1, N, H1, D1);
    pull1_kernel<<<blocks((long long)N * 32), TB, 0, stream>>>(
        rowptr, deg, esrc, el1, er1, feat1, b1, hbuf, N);

    // ---- layer 2 ----
    gemm_kernel<32><<<blocks((long long)N * D2), TB, 0, stream>>>(hbuf, W2, feat2, N, D2);
    attn_proj_kernel<<<blocks(N), TB, 0, stream>>>(feat2, al2, ar2, el2, er2, N, 1, D2);
    pull2_kernel<<<blocks((long long)N * 4), TB, 0, stream>>>(
        rowptr, deg, esrc, el2, er2, feat2, b2, (float*)d_out, N);
}

// Round 5
// 491.423 us; speedup vs baseline: 25.2711x; 1.1960x over previous
//
#include <hip/hip_runtime.h>
#include <hip/hip_bf16.h>

#define NEG_SLOPE 0.2f

// ---------- layer-1 GEMM (K=C=128) + fused el/er epilogue, bf16 feat out ----
// BM=64, BN=128, BK=32; 256 threads; thread tile 4x8.
__global__ __launch_bounds__(256) void gemm1_fused(
    const float* __restrict__ x, const float* __restrict__ W,
    const float* __restrict__ al, const float* __restrict__ ar,
    __hip_bfloat16* __restrict__ outb, float* __restrict__ el,
    float* __restrict__ er, int N) {
    const int K = 128, C = 128, BM = 64, BK = 32;
    __shared__ float xs[BK][BM + 4];
    __shared__ float ws[BK][C];

    const int t = threadIdx.x;
    const int trow = t >> 4;           // 0..15
    const int tcol = t & 15;           // 0..15
    const int m0 = blockIdx.x * BM;

    float acc[4][8];
#pragma unroll
    for (int i = 0; i < 4; ++i)
#pragma unroll
        for (int j = 0; j < 8; ++j) acc[i][j] = 0.f;

    for (int k0 = 0; k0 < K; k0 += BK) {
        {
            const float4* W4 = (const float4*)(W + k0 * C);
#pragma unroll
            for (int r = 0; r < 4; ++r) {
                int q = t + 256 * r;
                int k = q >> 5;
                int c4 = q & 31;
                float4 v = W4[k * 32 + c4];
                *((float4*)&ws[k][c4 * 4]) = v;
            }
        }
        {
#pragma unroll
            for (int r = 0; r < 2; ++r) {
                int q = t + 256 * r;
                int m = q >> 3;
                int k4 = q & 7;
                int gm = m0 + m;
                if (gm >= N) gm = N - 1;
                float4 v = *((const float4*)(x + (size_t)gm * K + k0 + k4 * 4));
                xs[k4 * 4 + 0][m] = v.x;
                xs[k4 * 4 + 1][m] = v.y;
                xs[k4 * 4 + 2][m] = v.z;
                xs[k4 * 4 + 3][m] = v.w;
            }
        }
        __syncthreads();

#pragma unroll
        for (int k = 0; k < BK; ++k) {
            float4 a = *((const float4*)&xs[k][trow * 4]);
            float4 b0 = *((const float4*)&ws[k][tcol * 8]);
            float4 b1 = *((const float4*)&ws[k][tcol * 8 + 4]);
            float av[4] = {a.x, a.y, a.z, a.w};
            float bv[8] = {b0.x, b0.y, b0.z, b0.w, b1.x, b1.y, b1.z, b1.w};
#pragma unroll
            for (int i = 0; i < 4; ++i)
#pragma unroll
                for (int j = 0; j < 8; ++j) acc[i][j] += av[i] * bv[j];
        }
        __syncthreads();
    }

    // epilogue: bf16 store + fused el/er
    const int h = tcol >> 2;               // head of this thread's 8 cols
    const int d0 = (tcol & 3) * 8;         // offset within head
    float alv[8], arv[8];
#pragma unroll
    for (int j = 0; j < 8; ++j) {
        alv[j] = al[h * 32 + d0 + j];
        arv[j] = ar[h * 32 + d0 + j];
    }
#pragma unroll
    for (int i = 0; i < 4; ++i) {
        int gm = m0 + trow * 4 + i;
        // bf16 feature store
        if (gm < N) {
            union { __hip_bfloat16 hh[8]; uint4 u; } pk;
#pragma unroll
            for (int j = 0; j < 8; ++j) pk.hh[j] = __float2bfloat16(acc[i][j]);
            *((uint4*)(outb + (size_t)gm * C + tcol * 8)) = pk.u;
        }
        // el/er partial + reduce over the 4 threads sharing (row, head)
        float pl = 0.f, pr = 0.f;
#pragma unroll
        for (int j = 0; j < 8; ++j) {
            pl += acc[i][j] * alv[j];
            pr += acc[i][j] * arv[j];
        }
        pl += __shfl_xor(pl, 1); pl += __shfl_xor(pl, 2);
        pr += __shfl_xor(pr, 1); pr += __shfl_xor(pr, 2);
        if ((tcol & 3) == 0 && gm < N) {
            el[gm * 4 + h] = pl;
            er[gm * 4 + h] = pr;
        }
    }
}

// ---------- layer-2 GEMM (K=32, C=16) + fused el/er (H=1) ----------
__global__ __launch_bounds__(256) void gemm2_fused(
    const float* __restrict__ x, const float* __restrict__ W,
    const float* __restrict__ al, const float* __restrict__ ar,
    float* __restrict__ out, float* __restrict__ el, float* __restrict__ er,
    int N) {
    const int K = 32, C = 16;
    int idx = blockIdx.x * blockDim.x + threadIdx.x;
    if (idx >= N * C) return;
    int n = idx / C, c = idx % C;
    const float* xr = x + (size_t)n * K;
    float acc = 0.f;
#pragma unroll
    for (int k = 0; k < K; ++k) acc += xr[k] * W[k * C + c];
    out[idx] = acc;
    float pl = acc * al[c];
    float pr = acc * ar[c];
    pl += __shfl_xor(pl, 1); pl += __shfl_xor(pl, 2);
    pl += __shfl_xor(pl, 4); pl += __shfl_xor(pl, 8);
    pr += __shfl_xor(pr, 1); pr += __shfl_xor(pr, 2);
    pr += __shfl_xor(pr, 4); pr += __shfl_xor(pr, 8);
    if (c == 0) {
        el[n] = pl;
        er[n] = pr;
    }
}

// ---------- CSR build ----------
__global__ __launch_bounds__(256) void hist_kernel(
    const int* __restrict__ dst, int* __restrict__ deg, int E) {
    int e = blockIdx.x * blockDim.x + threadIdx.x;
    if (e < E) atomicAdd(&deg[dst[e]], 1);
}

__global__ __launch_bounds__(256) void scan_block_kernel(
    const int* __restrict__ deg, int* __restrict__ rowptr,
    int* __restrict__ blocksum, int n) {
    __shared__ int tmp[256];
    int tid = threadIdx.x;
    int i = blockIdx.x * 256 + tid;
    int v = (i < n) ? deg[i] : 0;
    tmp[tid] = v;
    __syncthreads();
    for (int off = 1; off < 256; off <<= 1) {
        int t = (tid >= off) ? tmp[tid - off] : 0;
        __syncthreads();
        tmp[tid] += t;
        __syncthreads();
    }
    if (i < n) rowptr[i] = tmp[tid] - v;  // exclusive
    if (tid == 255) blocksum[blockIdx.x] = tmp[255];
}

__global__ __launch_bounds__(512) void scan_top_kernel(
    const int* __restrict__ blocksum, int* __restrict__ blockoff, int nb) {
    __shared__ int tmp[512];
    int tid = threadIdx.x;
    int v = (tid < nb) ? blocksum[tid] : 0;
    tmp[tid] = v;
    __syncthreads();
    for (int off = 1; off < 512; off <<= 1) {
        int t = (tid >= off) ? tmp[tid - off] : 0;
        __syncthreads();
        tmp[tid] += t;
        __syncthreads();
    }
    if (tid < nb) blockoff[tid] = tmp[tid] - v;
}

__global__ __launch_bounds__(256) void scan_add_kernel(
    int* __restrict__ rowptr, int* __restrict__ cursor,
    const int* __restrict__ blockoff, int n) {
    int i = blockIdx.x * 256 + threadIdx.x;
    if (i < n) {
        int r = rowptr[i] + blockoff[blockIdx.x];
        rowptr[i] = r;
        cursor[i] = r;
    }
}

__global__ __launch_bounds__(256) void scatter_kernel(
    const int* __restrict__ src, const int* __restrict__ dst,
    int* __restrict__ cursor, int* __restrict__ esrc, int E) {
    int e = blockIdx.x * blockDim.x + threadIdx.x;
    if (e >= E) return;
    int d = dst[e];
    int pos = atomicAdd(&cursor[d], 1);
    esrc[pos] = src[e];
}

// ---------- layer-1 pull: 32 lanes/node, 4 heads at once, bf16 feat ----------
__global__ __launch_bounds__(256) void pull1_kernel(
    const int* __restrict__ rowptr, const int* __restrict__ deg,
    const int* __restrict__ esrc, const float* __restrict__ el,
    const float* __restrict__ er, const __hip_bfloat16* __restrict__ featb,
    const float* __restrict__ b, float* __restrict__ hbuf, int N) {
    int tid = blockIdx.x * 256 + threadIdx.x;
    int node = tid >> 5;
    int lane = threadIdx.x & 31;
    int h = lane >> 3;
    int d4 = lane & 7;
    if (node >= N) return;

    int start = rowptr[node];
    int cnt = deg[node];
    float er_nh = er[node * 4 + h];
    const int* ep = esrc + start;
    const unsigned short* fb = (const unsigned short*)featb + h * 32 + d4 * 4;

    float4 acc = make_float4(0.f, 0.f, 0.f, 0.f);
    float sumex = 0.f;
    for (int i = 0; i < cnt; ++i) {
        int s = ep[i];
        float v = el[s * 4 + h] + er_nh;
        v = v > 0.f ? v : NEG_SLOPE * v;
        float ex = __expf(v);
        ushort4 u = *((const ushort4*)(fb + (size_t)s * 128));
        acc.x += ex * __uint_as_float((unsigned)u.x << 16);
        acc.y += ex * __uint_as_float((unsigned)u.y << 16);
        acc.z += ex * __uint_as_float((unsigned)u.z << 16);
        acc.w += ex * __uint_as_float((unsigned)u.w << 16);
        sumex += ex;
    }
    float inv = 1.f / ((sumex == 0.f) ? 1.f : sumex);
    float4 bb = *((const float4*)(b + h * 32 + d4 * 4));
    float4 o;
    o.x = acc.x * inv + bb.x;
    o.y = acc.y * inv + bb.y;
    o.z = acc.z * inv + bb.z;
    o.w = acc.w * inv + bb.w;
    // mean over heads (lanes differing in bits 3,4), then relu, lane h==0 stores
    o.x += __shfl_xor(o.x, 8); o.x += __shfl_xor(o.x, 16);
    o.y += __shfl_xor(o.y, 8); o.y += __shfl_xor(o.y, 16);
    o.z += __shfl_xor(o.z, 8); o.z += __shfl_xor(o.z, 16);
    o.w += __shfl_xor(o.w, 8); o.w += __shfl_xor(o.w, 16);
    if (h == 0) {
        o.x = fmaxf(o.x * 0.25f, 0.f);
        o.y = fmaxf(o.y * 0.25f, 0.f);
        o.z = fmaxf(o.z * 0.25f, 0.f);
        o.w = fmaxf(o.w * 0.25f, 0.f);
        *((float4*)(hbuf + (size_t)node * 32 + d4 * 4)) = o;
    }
}

// ---------- layer-2 pull: 4 lanes/node (H=1, D=16), fp32 feat ----------
__global__ __launch_bounds__(256) void pull2_kernel(
    const int* __restrict__ rowptr, const int* __restrict__ deg,
    const int* __restrict__ esrc, const float* __restrict__ el,
    const float* __restrict__ er, const float* __restrict__ feat,
    const float* __restrict__ b, float* __restrict__ outp, int N) {
    int tid = blockIdx.x * 256 + threadIdx.x;
    int node = tid >> 2;
    int d4 = threadIdx.x & 3;
    if (node >= N) return;

    int start = rowptr[node];
    int cnt = deg[node];
    float er_n = er[node];
    const int* ep = esrc + start;
    const float* fb = feat + d4 * 4;

    float4 acc = make_float4(0.f, 0.f, 0.f, 0.f);
    float sumex = 0.f;
    for (int i = 0; i < cnt; ++i) {
        int s = ep[i];
        float v = el[s] + er_n;
        v = v > 0.f ? v : NEG_SLOPE * v;
        float ex = __expf(v);
        float4 f = *((const float4*)(fb + (size_t)s * 16));
        acc.x += ex * f.x;
        acc.y += ex * f.y;
        acc.z += ex * f.z;
        acc.w += ex * f.w;
        sumex += ex;
    }
    float inv = 1.f / ((sumex == 0.f) ? 1.f : sumex);
    float4 bb = *((const float4*)(b + d4 * 4));
    float4 o;
    o.x = acc.x * inv + bb.x;
    o.y = acc.y * inv + bb.y;
    o.z = acc.z * inv + bb.z;
    o.w = acc.w * inv + bb.w;
    *((float4*)(outp + (size_t)node * 16 + d4 * 4)) = o;
}

extern "C" void kernel_launch(void* const* d_in, const int* in_sizes, int n_in,
                              void* d_out, int out_size, void* d_ws, size_t ws_size,
                              hipStream_t stream) {
    const float* x   = (const float*)d_in[0];
    const int*   src = (const int*)d_in[1];
    const int*   dst = (const int*)d_in[2];
    const float* W1  = (const float*)d_in[3];
    const float* al1 = (const float*)d_in[4];
    const float* ar1 = (const float*)d_in[5];
    const float* b1  = (const float*)d_in[6];
    const float* W2  = (const float*)d_in[7];
    const float* al2 = (const float*)d_in[8];
    const float* ar2 = (const float*)d_in[9];
    const float* b2  = (const float*)d_in[10];

    const int E = in_sizes[1];
    const int N = in_sizes[0] / 128;
    const int H1 = 4, D1 = 32, C1 = 128;
    const int D2 = 16;
    const int NBLK = (N + 255) / 256;

    // ---- workspace layout ----
    char* p = (char*)d_ws;
    auto alloc_f = [&](size_t n) { float* q = (float*)p; p += n * sizeof(float); return q; };
    auto alloc_i = [&](size_t n) { int* q = (int*)p; p += n * sizeof(int); return q; };

    __hip_bfloat16* feat1b = (__hip_bfloat16*)p; p += (size_t)N * C1 * sizeof(__hip_bfloat16);
    float* el1   = alloc_f((size_t)N * H1);
    float* er1   = alloc_f((size_t)N * H1);
    float* hbuf  = alloc_f((size_t)N * D1);
    float* feat2 = alloc_f((size_t)N * D2);
    float* el2   = alloc_f(N);
    float* er2   = alloc_f(N);
    int* deg     = alloc_i(N);
    int* rowptr  = alloc_i(N);
    int* cursor  = alloc_i(N);
    int* esrc    = alloc_i(E);
    int* blocksum = alloc_i(NBLK);
    int* blockoff = alloc_i(NBLK);

    const int TB = 256;
    auto blocks = [&](long long n) { return (int)((n + TB - 1) / TB); };

    // ---- CSR build (shared by both layers) ----
    hipMemsetAsync(deg, 0, (size_t)N * sizeof(int), stream);
    hist_kernel<<<blocks(E), TB, 0, stream>>>(dst, deg, E);
    scan_block_kernel<<<NBLK, TB, 0, stream>>>(deg, rowptr, blocksum, N);
    scan_top_kernel<<<1, 512, 0, stream>>>(blocksum, blockoff, NBLK);
    scan_add_kernel<<<NBLK, TB, 0, stream>>>(rowptr, cursor, blockoff, N);
    scatter_kernel<<<blocks(E), TB, 0, stream>>>(src, dst, cursor, esrc, E);

    // ---- layer 1 ----
    gemm1_fused<<<(N + 63) / 64, TB, 0, stream>>>(x, W1, al1, ar1, feat1b, el1, er1, N);
    pull1_kernel<<<blocks((long long)N * 32), TB, 0, stream>>>(
        rowptr, deg, esrc, el1, er1, feat1b, b1, hbuf, N);

    // ---- layer 2 ----
    gemm2_fused<<<blocks((long long)N * D2), TB, 0, stream>>>(hbuf, W2, al2, ar2,
                                                              feat2, el2, er2, N);
    pull2_kernel<<<blocks((long long)N * 4), TB, 0, stream>>>(
        rowptr, deg, esrc, el2, er2, feat2, b2, (float*)d_out, N);
}

// Round 6
// 345.059 us; speedup vs baseline: 35.9904x; 1.4242x over previous
//
#include <hip/hip_runtime.h>
#include <hip/hip_bf16.h>

#define NEG_SLOPE 0.2f
#define G_SHIFT 7
#define GSZ 128          // nodes per bucket
#define CHUNK 4096       // edges per coarse block; also per-bucket region capacity

// ---------- layer-1 GEMM (K=C=128) + fused el/er epilogue, bf16 feat out ----
__global__ __launch_bounds__(256) void gemm1_fused(
    const float* __restrict__ x, const float* __restrict__ W,
    const float* __restrict__ al, const float* __restrict__ ar,
    __hip_bfloat16* __restrict__ outb, float* __restrict__ el,
    float* __restrict__ er, int N) {
    const int K = 128, C = 128, BM = 64, BK = 32;
    __shared__ float xs[BK][BM + 4];
    __shared__ float ws[BK][C];

    const int t = threadIdx.x;
    const int trow = t >> 4;
    const int tcol = t & 15;
    const int m0 = blockIdx.x * BM;

    float acc[4][8];
#pragma unroll
    for (int i = 0; i < 4; ++i)
#pragma unroll
        for (int j = 0; j < 8; ++j) acc[i][j] = 0.f;

    for (int k0 = 0; k0 < K; k0 += BK) {
        {
            const float4* W4 = (const float4*)(W + k0 * C);
#pragma unroll
            for (int r = 0; r < 4; ++r) {
                int q = t + 256 * r;
                int k = q >> 5;
                int c4 = q & 31;
                float4 v = W4[k * 32 + c4];
                *((float4*)&ws[k][c4 * 4]) = v;
            }
        }
        {
#pragma unroll
            for (int r = 0; r < 2; ++r) {
                int q = t + 256 * r;
                int m = q >> 3;
                int k4 = q & 7;
                int gm = m0 + m;
                if (gm >= N) gm = N - 1;
                float4 v = *((const float4*)(x + (size_t)gm * K + k0 + k4 * 4));
                xs[k4 * 4 + 0][m] = v.x;
                xs[k4 * 4 + 1][m] = v.y;
                xs[k4 * 4 + 2][m] = v.z;
                xs[k4 * 4 + 3][m] = v.w;
            }
        }
        __syncthreads();

#pragma unroll
        for (int k = 0; k < BK; ++k) {
            float4 a = *((const float4*)&xs[k][trow * 4]);
            float4 b0 = *((const float4*)&ws[k][tcol * 8]);
            float4 b1 = *((const float4*)&ws[k][tcol * 8 + 4]);
            float av[4] = {a.x, a.y, a.z, a.w};
            float bv[8] = {b0.x, b0.y, b0.z, b0.w, b1.x, b1.y, b1.z, b1.w};
#pragma unroll
            for (int i = 0; i < 4; ++i)
#pragma unroll
                for (int j = 0; j < 8; ++j) acc[i][j] += av[i] * bv[j];
        }
        __syncthreads();
    }

    const int h = tcol >> 2;
    const int d0 = (tcol & 3) * 8;
    float alv[8], arv[8];
#pragma unroll
    for (int j = 0; j < 8; ++j) {
        alv[j] = al[h * 32 + d0 + j];
        arv[j] = ar[h * 32 + d0 + j];
    }
#pragma unroll
    for (int i = 0; i < 4; ++i) {
        int gm = m0 + trow * 4 + i;
        if (gm < N) {
            union { __hip_bfloat16 hh[8]; uint4 u; } pk;
#pragma unroll
            for (int j = 0; j < 8; ++j) pk.hh[j] = __float2bfloat16(acc[i][j]);
            *((uint4*)(outb + (size_t)gm * C + tcol * 8)) = pk.u;
        }
        float pl = 0.f, pr = 0.f;
#pragma unroll
        for (int j = 0; j < 8; ++j) {
            pl += acc[i][j] * alv[j];
            pr += acc[i][j] * arv[j];
        }
        pl += __shfl_xor(pl, 1); pl += __shfl_xor(pl, 2);
        pr += __shfl_xor(pr, 1); pr += __shfl_xor(pr, 2);
        if ((tcol & 3) == 0 && gm < N) {
            el[gm * 4 + h] = pl;
            er[gm * 4 + h] = pr;
        }
    }
}

// ---------- layer-2 GEMM (K=32, C=16) + fused el/er (H=1) ----------
__global__ __launch_bounds__(256) void gemm2_fused(
    const float* __restrict__ x, const float* __restrict__ W,
    const float* __restrict__ al, const float* __restrict__ ar,
    float* __restrict__ out, float* __restrict__ el, float* __restrict__ er,
    int N) {
    const int K = 32, C = 16;
    int idx = blockIdx.x * blockDim.x + threadIdx.x;
    if (idx >= N * C) return;
    int n = idx / C, c = idx % C;
    const float* xr = x + (size_t)n * K;
    float acc = 0.f;
#pragma unroll
    for (int k = 0; k < K; ++k) acc += xr[k] * W[k * C + c];
    out[idx] = acc;
    float pl = acc * al[c];
    float pr = acc * ar[c];
    pl += __shfl_xor(pl, 1); pl += __shfl_xor(pl, 2);
    pl += __shfl_xor(pl, 4); pl += __shfl_xor(pl, 8);
    pr += __shfl_xor(pr, 1); pr += __shfl_xor(pr, 2);
    pr += __shfl_xor(pr, 4); pr += __shfl_xor(pr, 8);
    if (c == 0) {
        el[n] = pl;
        er[n] = pr;
    }
}

// ---------- CSR build: LDS-aggregated two-level counting sort ----------
// Pass A: partition edges into dst-buckets of GSZ nodes; coalesced writes of
// (src,dst) into per-bucket regions of CHUNK capacity in `inter`.
__global__ __launch_bounds__(256) void coarse_scatter(
    const int* __restrict__ src, const int* __restrict__ dst,
    int* __restrict__ gcursor, uint2* __restrict__ inter, int NB, int E) {
    __shared__ int hist[800];    // bucket counts, later reused as rank cursor
    __shared__ int lbase[800];   // local exclusive prefix
    __shared__ int gbase[800];   // global slot base per bucket
    __shared__ uint2 stage[CHUNK];

    const int tid = threadIdx.x;
    const int e0 = blockIdx.x * CHUNK;
    const int cnt = min(CHUNK, E - e0);

    for (int i = tid; i < NB; i += 256) hist[i] = 0;
    __syncthreads();

    int ss[16], dd[16];
#pragma unroll
    for (int r = 0; r < 16; ++r) {
        int idx = tid + r * 256;
        if (idx < cnt) {
            ss[r] = src[e0 + idx];
            dd[r] = dst[e0 + idx];
            atomicAdd(&hist[dd[r] >> G_SHIFT], 1);
        }
    }
    __syncthreads();
    // exclusive scan of hist -> lbase (wave 0, shfl scan with carry)
    if (tid < 64) {
        int carry = 0;
        for (int i = 0; i < NB; i += 64) {
            int v = (i + tid < NB) ? hist[i + tid] : 0;
            int xv = v;
            for (int o = 1; o < 64; o <<= 1) {
                int tt = __shfl_up(xv, o, 64);
                if (tid >= o) xv += tt;
            }
            if (i + tid < NB) lbase[i + tid] = carry + xv - v;
            carry += __shfl(xv, 63, 64);
        }
    }
    __syncthreads();
    // reserve global space per bucket (few hundred small atomics per block)
    for (int i = tid; i < NB; i += 256) {
        int hh = hist[i];
        gbase[i] = (hh > 0) ? (i * CHUNK + atomicAdd(&gcursor[i], hh)) : 0;
    }
    __syncthreads();
    for (int i = tid; i < NB; i += 256) hist[i] = 0;  // reuse as cursor
    __syncthreads();
    // regroup into LDS stage by bucket
#pragma unroll
    for (int r = 0; r < 16; ++r) {
        int idx = tid + r * 256;
        if (idx < cnt) {
            int b = dd[r] >> G_SHIFT;
            int rk = atomicAdd(&hist[b], 1);
            stage[lbase[b] + rk] = make_uint2((unsigned)ss[r], (unsigned)dd[r]);
        }
    }
    __syncthreads();
    // coalesced write-out
#pragma unroll
    for (int r = 0; r < 16; ++r) {
        int idx = tid + r * 256;
        if (idx < cnt) {
            uint2 ed = stage[idx];
            int b = (int)(ed.y >> G_SHIFT);
            inter[gbase[b] + (idx - lbase[b])] = ed;
        }
    }
}

// Pass S: exclusive scan of bucket totals -> bucket_base (NB <= 1024)
__global__ __launch_bounds__(1024) void scan_buckets(
    const int* __restrict__ gcursor, int* __restrict__ bucket_base, int NB) {
    __shared__ int a[1024];
    int tid = threadIdx.x;
    int v = (tid < NB) ? gcursor[tid] : 0;
    a[tid] = v;
    __syncthreads();
    for (int o = 1; o < 1024; o <<= 1) {
        int t = (tid >= o) ? a[tid - o] : 0;
        __syncthreads();
        a[tid] += t;
        __syncthreads();
    }
    if (tid < NB) bucket_base[tid] = a[tid] - v;
}

// Pass C: one block per bucket. LDS node-hist -> deg/rowptr (coalesced) and
// LDS-staged esrc write (coalesced). No global atomics.
__global__ __launch_bounds__(256) void fine_scatter(
    const uint2* __restrict__ inter, const int* __restrict__ gcursor,
    const int* __restrict__ bucket_base, int* __restrict__ deg,
    int* __restrict__ rowptr, int* __restrict__ esrc, int N) {
    __shared__ int h[GSZ];
    __shared__ int lb[GSZ];
    __shared__ int stage[CHUNK];
    const int b = blockIdx.x;
    const int tid = threadIdx.x;
    const int cnt = gcursor[b];
    const int base = bucket_base[b];
    const uint2* ep = inter + (size_t)b * CHUNK;

    if (tid < GSZ) h[tid] = 0;
    __syncthreads();

    int ss[16];
    unsigned char ln[16];
    int nr = 0;
    for (int idx = tid; idx < cnt; idx += 256) {
        uint2 ed = ep[idx];
        ss[nr] = (int)ed.x;
        int l = (int)(ed.y & (GSZ - 1));
        ln[nr++] = (unsigned char)l;
        atomicAdd(&h[l], 1);
    }
    __syncthreads();
    // exclusive scan of 128 node counts (wave 0)
    if (tid < 64) {
        int carry = 0;
        for (int i = 0; i < GSZ; i += 64) {
            int v = h[i + tid];
            int xv = v;
            for (int o = 1; o < 64; o <<= 1) {
                int tt = __shfl_up(xv, o, 64);
                if (tid >= o) xv += tt;
            }
            lb[i + tid] = carry + xv - v;
            carry += __shfl(xv, 63, 64);
        }
    }
    __syncthreads();
    if (tid < GSZ) {
        int node = b * GSZ + tid;
        if (node < N) {
            deg[node] = h[tid];
            rowptr[node] = base + lb[tid];
        }
        h[tid] = 0;  // reuse as rank cursor (own-thread read happened above)
    }
    __syncthreads();
    for (int r = 0; r < nr; ++r) {
        int l = ln[r];
        int rk = atomicAdd(&h[l], 1);
        stage[lb[l] + rk] = ss[r];
    }
    __syncthreads();
    for (int idx = tid; idx < cnt; idx += 256) esrc[base + idx] = stage[idx];
}

// ---------- layer-1 pull: 32 lanes/node, 4 heads at once, bf16 feat ----------
__global__ __launch_bounds__(256) void pull1_kernel(
    const int* __restrict__ rowptr, const int* __restrict__ deg,
    const int* __restrict__ esrc, const float* __restrict__ el,
    const float* __restrict__ er, const __hip_bfloat16* __restrict__ featb,
    const float* __restrict__ b, float* __restrict__ hbuf, int N) {
    int tid = blockIdx.x * 256 + threadIdx.x;
    int node = tid >> 5;
    int lane = threadIdx.x & 31;
    int h = lane >> 3;
    int d4 = lane & 7;
    if (node >= N) return;

    int start = rowptr[node];
    int cnt = deg[node];
    float er_nh = er[node * 4 + h];
    const int* ep = esrc + start;
    const unsigned short* fb = (const unsigned short*)featb + h * 32 + d4 * 4;

    float4 acc = make_float4(0.f, 0.f, 0.f, 0.f);
    float sumex = 0.f;
    for (int i = 0; i < cnt; ++i) {
        int s = ep[i];
        float v = el[s * 4 + h] + er_nh;
        v = v > 0.f ? v : NEG_SLOPE * v;
        float ex = __expf(v);
        ushort4 u = *((const ushort4*)(fb + (size_t)s * 128));
        acc.x += ex * __uint_as_float((unsigned)u.x << 16);
        acc.y += ex * __uint_as_float((unsigned)u.y << 16);
        acc.z += ex * __uint_as_float((unsigned)u.z << 16);
        acc.w += ex * __uint_as_float((unsigned)u.w << 16);
        sumex += ex;
    }
    float inv = 1.f / ((sumex == 0.f) ? 1.f : sumex);
    float4 bb = *((const float4*)(b + h * 32 + d4 * 4));
    float4 o;
    o.x = acc.x * inv + bb.x;
    o.y = acc.y * inv + bb.y;
    o.z = acc.z * inv + bb.z;
    o.w = acc.w * inv + bb.w;
    o.x += __shfl_xor(o.x, 8); o.x += __shfl_xor(o.x, 16);
    o.y += __shfl_xor(o.y, 8); o.y += __shfl_xor(o.y, 16);
    o.z += __shfl_xor(o.z, 8); o.z += __shfl_xor(o.z, 16);
    o.w += __shfl_xor(o.w, 8); o.w += __shfl_xor(o.w, 16);
    if (h == 0) {
        o.x = fmaxf(o.x * 0.25f, 0.f);
        o.y = fmaxf(o.y * 0.25f, 0.f);
        o.z = fmaxf(o.z * 0.25f, 0.f);
        o.w = fmaxf(o.w * 0.25f, 0.f);
        *((float4*)(hbuf + (size_t)node * 32 + d4 * 4)) = o;
    }
}

// ---------- layer-2 pull: 4 lanes/node (H=1, D=16), fp32 feat ----------
__global__ __launch_bounds__(256) void pull2_kernel(
    const int* __restrict__ rowptr, const int* __restrict__ deg,
    const int* __restrict__ esrc, const float* __restrict__ el,
    const float* __restrict__ er, const float* __restrict__ feat,
    const float* __restrict__ b, float* __restrict__ outp, int N) {
    int tid = blockIdx.x * 256 + threadIdx.x;
    int node = tid >> 2;
    int d4 = threadIdx.x & 3;
    if (node >= N) return;

    int start = rowptr[node];
    int cnt = deg[node];
    float er_n = er[node];
    const int* ep = esrc + start;
    const float* fb = feat + d4 * 4;

    float4 acc = make_float4(0.f, 0.f, 0.f, 0.f);
    float sumex = 0.f;
    for (int i = 0; i < cnt; ++i) {
        int s = ep[i];
        float v = el[s] + er_n;
        v = v > 0.f ? v : NEG_SLOPE * v;
        float ex = __expf(v);
        float4 f = *((const float4*)(fb + (size_t)s * 16));
        acc.x += ex * f.x;
        acc.y += ex * f.y;
        acc.z += ex * f.z;
        acc.w += ex * f.w;
        sumex += ex;
    }
    float inv = 1.f / ((sumex == 0.f) ? 1.f : sumex);
    float4 bb = *((const float4*)(b + d4 * 4));
    float4 o;
    o.x = acc.x * inv + bb.x;
    o.y = acc.y * inv + bb.y;
    o.z = acc.z * inv + bb.z;
    o.w = acc.w * inv + bb.w;
    *((float4*)(outp + (size_t)node * 16 + d4 * 4)) = o;
}

extern "C" void kernel_launch(void* const* d_in, const int* in_sizes, int n_in,
                              void* d_out, int out_size, void* d_ws, size_t ws_size,
                              hipStream_t stream) {
    const float* x   = (const float*)d_in[0];
    const int*   src = (const int*)d_in[1];
    const int*   dst = (const int*)d_in[2];
    const float* W1  = (const float*)d_in[3];
    const float* al1 = (const float*)d_in[4];
    const float* ar1 = (const float*)d_in[5];
    const float* b1  = (const float*)d_in[6];
    const float* W2  = (const float*)d_in[7];
    const float* al2 = (const float*)d_in[8];
    const float* ar2 = (const float*)d_in[9];
    const float* b2  = (const float*)d_in[10];

    const int E = in_sizes[1];
    const int N = in_sizes[0] / 128;
    const int H1 = 4, D1 = 32, C1 = 128;
    const int D2 = 16;
    const int NB = (N + GSZ - 1) / GSZ;         // 782 buckets
    const int NCH = (E + CHUNK - 1) / CHUNK;    // 391 coarse blocks

    // ---- workspace layout ----
    char* p = (char*)d_ws;
    auto alloc_f = [&](size_t n) { float* q = (float*)p; p += n * sizeof(float); return q; };
    auto alloc_i = [&](size_t n) { int* q = (int*)p; p += n * sizeof(int); return q; };

    __hip_bfloat16* feat1b = (__hip_bfloat16*)p; p += (size_t)N * C1 * sizeof(__hip_bfloat16);
    float* el1   = alloc_f((size_t)N * H1);
    float* er1   = alloc_f((size_t)N * H1);
    float* hbuf  = alloc_f((size_t)N * D1);
    float* feat2 = alloc_f((size_t)N * D2);
    float* el2   = alloc_f(N);
    float* er2   = alloc_f(N);
    int* deg     = alloc_i(N);
    int* rowptr  = alloc_i(N);
    int* esrc    = alloc_i(E);
    int* gcursor = alloc_i(NB);
    int* bucket_base = alloc_i(NB);
    p = (char*)(((uintptr_t)p + 15) & ~(uintptr_t)15);
    uint2* inter = (uint2*)p; p += (size_t)NB * CHUNK * sizeof(uint2);

    const int TB = 256;
    auto blocks = [&](long long n) { return (int)((n + TB - 1) / TB); };

    // ---- CSR build (shared by both layers) ----
    hipMemsetAsync(gcursor, 0, (size_t)NB * sizeof(int), stream);
    coarse_scatter<<<NCH, TB, 0, stream>>>(src, dst, gcursor, inter, NB, E);
    scan_buckets<<<1, 1024, 0, stream>>>(gcursor, bucket_base, NB);
    fine_scatter<<<NB, TB, 0, stream>>>(inter, gcursor, bucket_base, deg, rowptr, esrc, N);

    // ---- layer 1 ----
    gemm1_fused<<<(N + 63) / 64, TB, 0, stream>>>(x, W1, al1, ar1, feat1b, el1, er1, N);
    pull1_kernel<<<blocks((long long)N * 32), TB, 0, stream>>>(
        rowptr, deg, esrc, el1, er1, feat1b, b1, hbuf, N);

    // ---- layer 2 ----
    gemm2_fused<<<blocks((long long)N * D2), TB, 0, stream>>>(hbuf, W2, al2, ar2,
                                                              feat2, el2, er2, N);
    pull2_kernel<<<blocks((long long)N * 4), TB, 0, stream>>>(
        rowptr, deg, esrc, el2, er2, feat2, b2, (float*)d_out, N);
}

// Round 7
// 303.407 us; speedup vs baseline: 40.9311x; 1.1373x over previous
//
#include <hip/hip_runtime.h>
#include <hip/hip_bf16.h>

#define NEG_SLOPE 0.2f
#define G_SHIFT 7
#define GSZ 128          // nodes per bucket
#define CHUNK 4096       // edges per coarse block; also per-bucket region capacity

// ---------- layer-1 GEMM (K=C=128) + fused el/er epilogue, bf16 feat out ----
__global__ __launch_bounds__(256) void gemm1_fused(
    const float* __restrict__ x, const float* __restrict__ W,
    const float* __restrict__ al, const float* __restrict__ ar,
    __hip_bfloat16* __restrict__ outb, float* __restrict__ el,
    float* __restrict__ er, int N) {
    const int K = 128, C = 128, BM = 64, BK = 32;
    __shared__ float xs[BK][BM + 4];
    __shared__ float ws[BK][C];

    const int t = threadIdx.x;
    const int trow = t >> 4;
    const int tcol = t & 15;
    const int m0 = blockIdx.x * BM;

    float acc[4][8];
#pragma unroll
    for (int i = 0; i < 4; ++i)
#pragma unroll
        for (int j = 0; j < 8; ++j) acc[i][j] = 0.f;

    for (int k0 = 0; k0 < K; k0 += BK) {
        {
            const float4* W4 = (const float4*)(W + k0 * C);
#pragma unroll
            for (int r = 0; r < 4; ++r) {
                int q = t + 256 * r;
                int k = q >> 5;
                int c4 = q & 31;
                float4 v = W4[k * 32 + c4];
                *((float4*)&ws[k][c4 * 4]) = v;
            }
        }
        {
#pragma unroll
            for (int r = 0; r < 2; ++r) {
                int q = t + 256 * r;
                int m = q >> 3;
                int k4 = q & 7;
                int gm = m0 + m;
                if (gm >= N) gm = N - 1;
                float4 v = *((const float4*)(x + (size_t)gm * K + k0 + k4 * 4));
                xs[k4 * 4 + 0][m] = v.x;
                xs[k4 * 4 + 1][m] = v.y;
                xs[k4 * 4 + 2][m] = v.z;
                xs[k4 * 4 + 3][m] = v.w;
            }
        }
        __syncthreads();

#pragma unroll
        for (int k = 0; k < BK; ++k) {
            float4 a = *((const float4*)&xs[k][trow * 4]);
            float4 b0 = *((const float4*)&ws[k][tcol * 8]);
            float4 b1 = *((const float4*)&ws[k][tcol * 8 + 4]);
            float av[4] = {a.x, a.y, a.z, a.w};
            float bv[8] = {b0.x, b0.y, b0.z, b0.w, b1.x, b1.y, b1.z, b1.w};
#pragma unroll
            for (int i = 0; i < 4; ++i)
#pragma unroll
                for (int j = 0; j < 8; ++j) acc[i][j] += av[i] * bv[j];
        }
        __syncthreads();
    }

    const int h = tcol >> 2;
    const int d0 = (tcol & 3) * 8;
    float alv[8], arv[8];
#pragma unroll
    for (int j = 0; j < 8; ++j) {
        alv[j] = al[h * 32 + d0 + j];
        arv[j] = ar[h * 32 + d0 + j];
    }
#pragma unroll
    for (int i = 0; i < 4; ++i) {
        int gm = m0 + trow * 4 + i;
        if (gm < N) {
            union { __hip_bfloat16 hh[8]; uint4 u; } pk;
#pragma unroll
            for (int j = 0; j < 8; ++j) pk.hh[j] = __float2bfloat16(acc[i][j]);
            *((uint4*)(outb + (size_t)gm * C + tcol * 8)) = pk.u;
        }
        float pl = 0.f, pr = 0.f;
#pragma unroll
        for (int j = 0; j < 8; ++j) {
            pl += acc[i][j] * alv[j];
            pr += acc[i][j] * arv[j];
        }
        pl += __shfl_xor(pl, 1); pl += __shfl_xor(pl, 2);
        pr += __shfl_xor(pr, 1); pr += __shfl_xor(pr, 2);
        if ((tcol & 3) == 0 && gm < N) {
            el[gm * 4 + h] = pl;
            er[gm * 4 + h] = pr;
        }
    }
}

// ---------- layer-2 GEMM (K=32, C=16) + fused el/er (H=1) ----------
__global__ __launch_bounds__(256) void gemm2_fused(
    const float* __restrict__ x, const float* __restrict__ W,
    const float* __restrict__ al, const float* __restrict__ ar,
    float* __restrict__ out, float* __restrict__ el, float* __restrict__ er,
    int N) {
    const int K = 32, C = 16;
    int idx = blockIdx.x * blockDim.x + threadIdx.x;
    if (idx >= N * C) return;
    int n = idx / C, c = idx % C;
    const float* xr = x + (size_t)n * K;
    float acc = 0.f;
#pragma unroll
    for (int k = 0; k < K; ++k) acc += xr[k] * W[k * C + c];
    out[idx] = acc;
    float pl = acc * al[c];
    float pr = acc * ar[c];
    pl += __shfl_xor(pl, 1); pl += __shfl_xor(pl, 2);
    pl += __shfl_xor(pl, 4); pl += __shfl_xor(pl, 8);
    pr += __shfl_xor(pr, 1); pr += __shfl_xor(pr, 2);
    pr += __shfl_xor(pr, 4); pr += __shfl_xor(pr, 8);
    if (c == 0) {
        el[n] = pl;
        er[n] = pr;
    }
}

// ---------- CSR build: LDS-aggregated two-level counting sort ----------
__global__ __launch_bounds__(256) void coarse_scatter(
    const int* __restrict__ src, const int* __restrict__ dst,
    int* __restrict__ gcursor, uint2* __restrict__ inter, int NB, int E) {
    __shared__ int hist[800];
    __shared__ int lbase[800];
    __shared__ int gbase[800];
    __shared__ uint2 stage[CHUNK];

    const int tid = threadIdx.x;
    const int e0 = blockIdx.x * CHUNK;
    const int cnt = min(CHUNK, E - e0);

    for (int i = tid; i < NB; i += 256) hist[i] = 0;
    __syncthreads();

    int ss[16], dd[16];
#pragma unroll
    for (int r = 0; r < 16; ++r) {
        int idx = tid + r * 256;
        if (idx < cnt) {
            ss[r] = src[e0 + idx];
            dd[r] = dst[e0 + idx];
            atomicAdd(&hist[dd[r] >> G_SHIFT], 1);
        }
    }
    __syncthreads();
    if (tid < 64) {
        int carry = 0;
        for (int i = 0; i < NB; i += 64) {
            int v = (i + tid < NB) ? hist[i + tid] : 0;
            int xv = v;
            for (int o = 1; o < 64; o <<= 1) {
                int tt = __shfl_up(xv, o, 64);
                if (tid >= o) xv += tt;
            }
            if (i + tid < NB) lbase[i + tid] = carry + xv - v;
            carry += __shfl(xv, 63, 64);
        }
    }
    __syncthreads();
    for (int i = tid; i < NB; i += 256) {
        int hh = hist[i];
        gbase[i] = (hh > 0) ? (i * CHUNK + atomicAdd(&gcursor[i], hh)) : 0;
    }
    __syncthreads();
    for (int i = tid; i < NB; i += 256) hist[i] = 0;
    __syncthreads();
#pragma unroll
    for (int r = 0; r < 16; ++r) {
        int idx = tid + r * 256;
        if (idx < cnt) {
            int b = dd[r] >> G_SHIFT;
            int rk = atomicAdd(&hist[b], 1);
            stage[lbase[b] + rk] = make_uint2((unsigned)ss[r], (unsigned)dd[r]);
        }
    }
    __syncthreads();
#pragma unroll
    for (int r = 0; r < 16; ++r) {
        int idx = tid + r * 256;
        if (idx < cnt) {
            uint2 ed = stage[idx];
            int b = (int)(ed.y >> G_SHIFT);
            inter[gbase[b] + (idx - lbase[b])] = ed;
        }
    }
}

__global__ __launch_bounds__(1024) void scan_buckets(
    const int* __restrict__ gcursor, int* __restrict__ bucket_base, int NB) {
    __shared__ int a[1024];
    int tid = threadIdx.x;
    int v = (tid < NB) ? gcursor[tid] : 0;
    a[tid] = v;
    __syncthreads();
    for (int o = 1; o < 1024; o <<= 1) {
        int t = (tid >= o) ? a[tid - o] : 0;
        __syncthreads();
        a[tid] += t;
        __syncthreads();
    }
    if (tid < NB) bucket_base[tid] = a[tid] - v;
}

__global__ __launch_bounds__(256) void fine_scatter(
    const uint2* __restrict__ inter, const int* __restrict__ gcursor,
    const int* __restrict__ bucket_base, int* __restrict__ deg,
    int* __restrict__ rowptr, int* __restrict__ esrc, int N) {
    __shared__ int h[GSZ];
    __shared__ int lb[GSZ];
    __shared__ int stage[CHUNK];
    const int b = blockIdx.x;
    const int tid = threadIdx.x;
    const int cnt = gcursor[b];
    const int base = bucket_base[b];
    const uint2* ep = inter + (size_t)b * CHUNK;

    if (tid < GSZ) h[tid] = 0;
    __syncthreads();

    int ss[16];
    unsigned char ln[16];
    int nr = 0;
    for (int idx = tid; idx < cnt; idx += 256) {
        uint2 ed = ep[idx];
        ss[nr] = (int)ed.x;
        int l = (int)(ed.y & (GSZ - 1));
        ln[nr++] = (unsigned char)l;
        atomicAdd(&h[l], 1);
    }
    __syncthreads();
    if (tid < 64) {
        int carry = 0;
        for (int i = 0; i < GSZ; i += 64) {
            int v = h[i + tid];
            int xv = v;
            for (int o = 1; o < 64; o <<= 1) {
                int tt = __shfl_up(xv, o, 64);
                if (tid >= o) xv += tt;
            }
            lb[i + tid] = carry + xv - v;
            carry += __shfl(xv, 63, 64);
        }
    }
    __syncthreads();
    if (tid < GSZ) {
        int node = b * GSZ + tid;
        if (node < N) {
            deg[node] = h[tid];
            rowptr[node] = base + lb[tid];
        }
        h[tid] = 0;
    }
    __syncthreads();
    for (int r = 0; r < nr; ++r) {
        int l = ln[r];
        int rk = atomicAdd(&h[l], 1);
        stage[lb[l] + rk] = ss[r];
    }
    __syncthreads();
    for (int idx = tid; idx < cnt; idx += 256) esrc[base + idx] = stage[idx];
}

// ---------- layer-1 pull: 32 lanes/node, 4 heads, bf16 feat, 4x MLP unroll ---
__global__ __launch_bounds__(256) void pull1_kernel(
    const int* __restrict__ rowptr, const int* __restrict__ deg,
    const int* __restrict__ esrc, const float* __restrict__ el,
    const float* __restrict__ er, const __hip_bfloat16* __restrict__ featb,
    const float* __restrict__ b, float* __restrict__ hbuf, int N) {
    int tid = blockIdx.x * 256 + threadIdx.x;
    int node = tid >> 5;
    int lane = threadIdx.x & 31;
    int h = lane >> 3;
    int d4 = lane & 7;
    if (node >= N) return;

    int start = rowptr[node];
    int cnt = deg[node];
    float er_nh = er[node * 4 + h];
    const int* ep = esrc + start;
    const unsigned short* fb = (const unsigned short*)featb + h * 32 + d4 * 4;

    float4 acc = make_float4(0.f, 0.f, 0.f, 0.f);
    float sumex = 0.f;

    int i = 0;
    for (; i + 4 <= cnt; i += 4) {
        int s0 = ep[i], s1 = ep[i + 1], s2 = ep[i + 2], s3 = ep[i + 3];
        float e0 = el[s0 * 4 + h], e1 = el[s1 * 4 + h];
        float e2 = el[s2 * 4 + h], e3 = el[s3 * 4 + h];
        ushort4 u0 = *((const ushort4*)(fb + (size_t)s0 * 128));
        ushort4 u1 = *((const ushort4*)(fb + (size_t)s1 * 128));
        ushort4 u2 = *((const ushort4*)(fb + (size_t)s2 * 128));
        ushort4 u3 = *((const ushort4*)(fb + (size_t)s3 * 128));
        float v0 = e0 + er_nh; v0 = v0 > 0.f ? v0 : NEG_SLOPE * v0;
        float v1 = e1 + er_nh; v1 = v1 > 0.f ? v1 : NEG_SLOPE * v1;
        float v2 = e2 + er_nh; v2 = v2 > 0.f ? v2 : NEG_SLOPE * v2;
        float v3 = e3 + er_nh; v3 = v3 > 0.f ? v3 : NEG_SLOPE * v3;
        float x0 = __expf(v0), x1 = __expf(v1), x2 = __expf(v2), x3 = __expf(v3);
        acc.x += x0 * __uint_as_float((unsigned)u0.x << 16);
        acc.y += x0 * __uint_as_float((unsigned)u0.y << 16);
        acc.z += x0 * __uint_as_float((unsigned)u0.z << 16);
        acc.w += x0 * __uint_as_float((unsigned)u0.w << 16);
        acc.x += x1 * __uint_as_float((unsigned)u1.x << 16);
        acc.y += x1 * __uint_as_float((unsigned)u1.y << 16);
        acc.z += x1 * __uint_as_float((unsigned)u1.z << 16);
        acc.w += x1 * __uint_as_float((unsigned)u1.w << 16);
        acc.x += x2 * __uint_as_float((unsigned)u2.x << 16);
        acc.y += x2 * __uint_as_float((unsigned)u2.y << 16);
        acc.z += x2 * __uint_as_float((unsigned)u2.z << 16);
        acc.w += x2 * __uint_as_float((unsigned)u2.w << 16);
        acc.x += x3 * __uint_as_float((unsigned)u3.x << 16);
        acc.y += x3 * __uint_as_float((unsigned)u3.y << 16);
        acc.z += x3 * __uint_as_float((unsigned)u3.z << 16);
        acc.w += x3 * __uint_as_float((unsigned)u3.w << 16);
        sumex += x0 + x1 + x2 + x3;
    }
    for (; i < cnt; ++i) {
        int s = ep[i];
        float v = el[s * 4 + h] + er_nh;
        v = v > 0.f ? v : NEG_SLOPE * v;
        float ex = __expf(v);
        ushort4 u = *((const ushort4*)(fb + (size_t)s * 128));
        acc.x += ex * __uint_as_float((unsigned)u.x << 16);
        acc.y += ex * __uint_as_float((unsigned)u.y << 16);
        acc.z += ex * __uint_as_float((unsigned)u.z << 16);
        acc.w += ex * __uint_as_float((unsigned)u.w << 16);
        sumex += ex;
    }
    float inv = 1.f / ((sumex == 0.f) ? 1.f : sumex);
    float4 bb = *((const float4*)(b + h * 32 + d4 * 4));
    float4 o;
    o.x = acc.x * inv + bb.x;
    o.y = acc.y * inv + bb.y;
    o.z = acc.z * inv + bb.z;
    o.w = acc.w * inv + bb.w;
    o.x += __shfl_xor(o.x, 8); o.x += __shfl_xor(o.x, 16);
    o.y += __shfl_xor(o.y, 8); o.y += __shfl_xor(o.y, 16);
    o.z += __shfl_xor(o.z, 8); o.z += __shfl_xor(o.z, 16);
    o.w += __shfl_xor(o.w, 8); o.w += __shfl_xor(o.w, 16);
    if (h == 0) {
        o.x = fmaxf(o.x * 0.25f, 0.f);
        o.y = fmaxf(o.y * 0.25f, 0.f);
        o.z = fmaxf(o.z * 0.25f, 0.f);
        o.w = fmaxf(o.w * 0.25f, 0.f);
        *((float4*)(hbuf + (size_t)node * 32 + d4 * 4)) = o;
    }
}

// ---------- layer-2 pull: 4 lanes/node (H=1, D=16), fp32 feat, 4x unroll -----
__global__ __launch_bounds__(256) void pull2_kernel(
    const int* __restrict__ rowptr, const int* __restrict__ deg,
    const int* __restrict__ esrc, const float* __restrict__ el,
    const float* __restrict__ er, const float* __restrict__ feat,
    const float* __restrict__ b, float* __restrict__ outp, int N) {
    int tid = blockIdx.x * 256 + threadIdx.x;
    int node = tid >> 2;
    int d4 = threadIdx.x & 3;
    if (node >= N) return;

    int start = rowptr[node];
    int cnt = deg[node];
    float er_n = er[node];
    const int* ep = esrc + start;
    const float* fb = feat + d4 * 4;

    float4 acc = make_float4(0.f, 0.f, 0.f, 0.f);
    float sumex = 0.f;
    int i = 0;
    for (; i + 4 <= cnt; i += 4) {
        int s0 = ep[i], s1 = ep[i + 1], s2 = ep[i + 2], s3 = ep[i + 3];
        float e0 = el[s0], e1 = el[s1], e2 = el[s2], e3 = el[s3];
        float4 f0 = *((const float4*)(fb + (size_t)s0 * 16));
        float4 f1 = *((const float4*)(fb + (size_t)s1 * 16));
        float4 f2 = *((const float4*)(fb + (size_t)s2 * 16));
        float4 f3 = *((const float4*)(fb + (size_t)s3 * 16));
        float v0 = e0 + er_n; v0 = v0 > 0.f ? v0 : NEG_SLOPE * v0;
        float v1 = e1 + er_n; v1 = v1 > 0.f ? v1 : NEG_SLOPE * v1;
        float v2 = e2 + er_n; v2 = v2 > 0.f ? v2 : NEG_SLOPE * v2;
        float v3 = e3 + er_n; v3 = v3 > 0.f ? v3 : NEG_SLOPE * v3;
        float x0 = __expf(v0), x1 = __expf(v1), x2 = __expf(v2), x3 = __expf(v3);
        acc.x += x0 * f0.x; acc.y += x0 * f0.y; acc.z += x0 * f0.z; acc.w += x0 * f0.w;
        acc.x += x1 * f1.x; acc.y += x1 * f1.y; acc.z += x1 * f1.z; acc.w += x1 * f1.w;
        acc.x += x2 * f2.x; acc.y += x2 * f2.y; acc.z += x2 * f2.z; acc.w += x2 * f2.w;
        acc.x += x3 * f3.x; acc.y += x3 * f3.y; acc.z += x3 * f3.z; acc.w += x3 * f3.w;
        sumex += x0 + x1 + x2 + x3;
    }
    for (; i < cnt; ++i) {
        int s = ep[i];
        float v = el[s] + er_n;
        v = v > 0.f ? v : NEG_SLOPE * v;
        float ex = __expf(v);
        float4 f = *((const float4*)(fb + (size_t)s * 16));
        acc.x += ex * f.x;
        acc.y += ex * f.y;
        acc.z += ex * f.z;
        acc.w += ex * f.w;
        sumex += ex;
    }
    float inv = 1.f / ((sumex == 0.f) ? 1.f : sumex);
    float4 bb = *((const float4*)(b + d4 * 4));
    float4 o;
    o.x = acc.x * inv + bb.x;
    o.y = acc.y * inv + bb.y;
    o.z = acc.z * inv + bb.z;
    o.w = acc.w * inv + bb.w;
    *((float4*)(outp + (size_t)node * 16 + d4 * 4)) = o;
}

extern "C" void kernel_launch(void* const* d_in, const int* in_sizes, int n_in,
                              void* d_out, int out_size, void* d_ws, size_t ws_size,
                              hipStream_t stream) {
    const float* x   = (const float*)d_in[0];
    const int*   src = (const int*)d_in[1];
    const int*   dst = (const int*)d_in[2];
    const float* W1  = (const float*)d_in[3];
    const float* al1 = (const float*)d_in[4];
    const float* ar1 = (const float*)d_in[5];
    const float* b1  = (const float*)d_in[6];
    const float* W2  = (const float*)d_in[7];
    const float* al2 = (const float*)d_in[8];
    const float* ar2 = (const float*)d_in[9];
    const float* b2  = (const float*)d_in[10];

    const int E = in_sizes[1];
    const int N = in_sizes[0] / 128;
    const int H1 = 4, D1 = 32, C1 = 128;
    const int D2 = 16;
    const int NB = (N + GSZ - 1) / GSZ;
    const int NCH = (E + CHUNK - 1) / CHUNK;

    char* p = (char*)d_ws;
    auto alloc_f = [&](size_t n) { float* q = (float*)p; p += n * sizeof(float); return q; };
    auto alloc_i = [&](size_t n) { int* q = (int*)p; p += n * sizeof(int); return q; };

    __hip_bfloat16* feat1b = (__hip_bfloat16*)p; p += (size_t)N * C1 * sizeof(__hip_bfloat16);
    float* el1   = alloc_f((size_t)N * H1);
    float* er1   = alloc_f((size_t)N * H1);
    float* hbuf  = alloc_f((size_t)N * D1);
    float* feat2 = alloc_f((size_t)N * D2);
    float* el2   = alloc_f(N);
    float* er2   = alloc_f(N);
    int* deg     = alloc_i(N);
    int* rowptr  = alloc_i(N);
    int* esrc    = alloc_i(E);
    int* gcursor = alloc_i(NB);
    int* bucket_base = alloc_i(NB);
    p = (char*)(((uintptr_t)p + 15) & ~(uintptr_t)15);
    uint2* inter = (uint2*)p; p += (size_t)NB * CHUNK * sizeof(uint2);

    const int TB = 256;
    auto blocks = [&](long long n) { return (int)((n + TB - 1) / TB); };

    // ---- CSR build (shared by both layers) ----
    hipMemsetAsync(gcursor, 0, (size_t)NB * sizeof(int), stream);
    coarse_scatter<<<NCH, TB, 0, stream>>>(src, dst, gcursor, inter, NB, E);
    scan_buckets<<<1, 1024, 0, stream>>>(gcursor, bucket_base, NB);
    fine_scatter<<<NB, TB, 0, stream>>>(inter, gcursor, bucket_base, deg, rowptr, esrc, N);

    // ---- layer 1 ----
    gemm1_fused<<<(N + 63) / 64, TB, 0, stream>>>(x, W1, al1, ar1, feat1b, el1, er1, N);
    pull1_kernel<<<blocks((long long)N * 32), TB, 0, stream>>>(
        rowptr, deg, esrc, el1, er1, feat1b, b1, hbuf, N);

    // ---- layer 2 ----
    gemm2_fused<<<blocks((long long)N * D2), TB, 0, stream>>>(hbuf, W2, al2, ar2,
                                                              feat2, el2, er2, N);
    pull2_kernel<<<blocks((long long)N * 4), TB, 0, stream>>>(
        rowptr, deg, esrc, el2, er2, feat2, b2, (float*)d_out, N);
}